// Round 11
// baseline (8268.974 us; speedup 1.0000x reference)
//
#include <hip/hip_runtime.h>
#include <hip/hip_bf16.h>
#include <hip/hip_cooperative_groups.h>

namespace cg = cooperative_groups;

typedef unsigned short u16;
typedef unsigned int u32;
typedef __attribute__((ext_vector_type(8))) short bh8;     // 8 x bf16 MFMA A/B frag
typedef __attribute__((ext_vector_type(4))) float f32x4;   // MFMA C/D frag

#define KB_T 0.025851f
#define HS (1024 * 512)

// d_out (fp32): preds.T [1024][32] | E [1024] | gens.T [1024][32] | bps.T [1024][32]
#define OFF_E    32768
#define OFF_GENS 33792
#define OFF_BPS  66560

// ---- workspace layout (byte offsets)
#define WS_WP     0u         // [2048][256] bf16  (W_ih0[:,1:])
#define WS_FW1T   1048576u   // [256][512] bf16   (fW1[1:] ^T)
#define WS_FW2T   1310720u   // [256][256] bf16   (fW2 ^T)
#define WS_FW1R0  1441792u   // [256] f32         (fW1 row 0)
#define WS_W0COL  1442816u   // [2048] f32        (W_ih0[:,0])
#define WS_EE     1451008u   // [1024] f32
#define WS_RATE   1455104u   // [1024] f32
#define WS_SP     1459200u   // [1024] f32
#define WS_H0     1463296u   // 2x[1024][512] bf16 ping-pong
#define WS_H1     3560448u   // 2x[1024][512] bf16
#define WS_C0     5657600u   // [1024][512] bf16
#define WS_C1     6706176u   // [1024][512] bf16
#define WS_BASE_END 7754752u
#define WS_WIH1B  7754752u   // [2048][512] bf16
#define WS_WHH1B  9851904u
#define WS_T1_END 11949056u
#define WS_WHH0B  11949056u
#define WS_T2_END 14046208u
#define WS_LATB   14046208u  // [1024][256] bf16
#define WS_T3_END 14570496u

__device__ __forceinline__ float b2f(u16 u) { u32 x = ((u32)u) << 16; float f; __builtin_memcpy(&f, &x, 4); return f; }
__device__ __forceinline__ u16 f2b(float f) { __hip_bfloat16 h = __float2bfloat16(f); u16 u; __builtin_memcpy(&u, &h, 2); return u; }
__device__ __forceinline__ float sigf(float x) { return 1.f / (1.f + __expf(-x)); }
__device__ __forceinline__ float tanh_(float x) { return 1.f - 2.f / (__expf(2.f * x) + 1.f); }
__device__ __forceinline__ float gelu_(float x) { return 0.5f * x * (1.f + tanh_(0.7978845608f * (x + 0.044715f * x * x * x))); }

__device__ __forceinline__ void stage8(u16* dst, const void* src, int ofs, int srcf32) {
    if (srcf32) {
        const float* s = (const float*)src + ofs;
        float4 a = *(const float4*)s;
        float4 b = *(const float4*)(s + 4);
        u16 t[8] = {f2b(a.x), f2b(a.y), f2b(a.z), f2b(a.w),
                    f2b(b.x), f2b(b.y), f2b(b.z), f2b(b.w)};
        *(float4*)dst = *(const float4*)t;
    } else {
        *(float4*)dst = *(const float4*)((const u16*)src + ofs);
    }
}

// ---------------------------------------------------------------------------
// setup: zero states; repack W_ih0 -> Wp+w0col; fW1 -> fW1t+fw1r0; fW2 -> fW2t;
// lat -> latb (bf16); E/rate/s0. grid 2048 x 256.
// ---------------------------------------------------------------------------
__global__ __launch_bounds__(256) void k_setup(
    const float* __restrict__ ist, const float* __restrict__ lat,
    const float* __restrict__ vol, const float* __restrict__ thick,
    const float* __restrict__ trap, const float* __restrict__ W_ih0,
    const float* __restrict__ fW1, const float* __restrict__ fW2,
    u16* __restrict__ h0, u16* __restrict__ h1, u16* __restrict__ c0, u16* __restrict__ c1,
    u16* __restrict__ Wp, float* __restrict__ w0col,
    u16* __restrict__ fW1t, u16* __restrict__ fW2t, float* __restrict__ fw1r0,
    u16* __restrict__ latb,
    float* __restrict__ Ee, float* __restrict__ ratep, float* __restrict__ sp,
    float* __restrict__ outE)
{
    const int idx = blockIdx.x * 256 + threadIdx.x;
    h0[idx] = 0; h1[idx] = 0; c0[idx] = 0; c1[idx] = 0;
    Wp[idx] = f2b(W_ih0[(idx >> 8) * 257 + 1 + (idx & 255)]);
    if (idx < 262144 && latb) latb[idx] = f2b(lat[idx]);
    if (idx < 131072) { int n = idx >> 9, k = idx & 511; fW1t[n * 512 + k] = f2b(fW1[(1 + k) * 256 + n]); }
    if (idx < 65536)  { int n = idx >> 8, k = idx & 255; fW2t[n * 256 + k] = f2b(fW2[k * 256 + n]); }
    if (idx < 2048)   w0col[idx] = W_ih0[idx * 257];
    if (idx < 256)    fw1r0[idx] = fW1[idx];
    if (idx < 1024) {
        float E = vol[idx] / thick[idx];
        float Ea = trap[idx * 8], ga = trap[idx * 8 + 1];
        ratep[idx] = __expf(-fmaxf(Ea - ga * E, 0.f) / KB_T);
        Ee[idx] = E;
        sp[idx] = ist[idx * 10 + 9];
        outE[idx] = E;
    }
}

// fp32 -> bf16 convert of three [2048][512] weights. grid 12288 x 256.
__global__ __launch_bounds__(256) void k_conv3w(
    const float* __restrict__ a, const float* __restrict__ b, const float* __restrict__ c,
    u16* __restrict__ oa, u16* __restrict__ ob, u16* __restrict__ oc)
{
    const int idx = blockIdx.x * 256 + threadIdx.x;
    const int w = idx >> 20, i = idx & 1048575;
    if (w == 0)      oa[i] = f2b(a[i]);
    else if (w == 1) ob[i] = f2b(b[i]);
    else             oc[i] = f2b(c[i]);
}

// ===========================================================================
// Device tiles
// ===========================================================================

// LSTM tile 64 rows x 128 gate-cols (4 gates x 32 j), BK=128, waves 2x2
// (each wave 32 rows x 64 gate-cols, acc 2x4). LDS: A[64][136] + B[128][136].
__device__ __forceinline__ void lstm_tile64(
    char* smem, int j0, int row0,
    const u16* __restrict__ A1, int lda1, int nk1, const u16* __restrict__ W1, int ldw1,
    const u16* __restrict__ A2, int lda2, int nk2, const u16* __restrict__ W2, int ldw2,
    const float* __restrict__ w0col, const float* __restrict__ s, const float* __restrict__ bias,
    u16* __restrict__ c, u16* __restrict__ hout)
{
    u16*   ldsA = (u16*)smem;                // [64][136], 17408 B
    u16*   ldsB = (u16*)(smem + 17408);      // [128][136], 34816 B
    float* gbuf = (float*)smem;              // [64][132] f32 overlay, 33792 B

    const int tid = threadIdx.x, wid = tid >> 6, lane = tid & 63;
    const int q = lane >> 4, ln = lane & 15;
    const int wr = wid >> 1, wc = wid & 1;

    f32x4 acc[2][4];
#pragma unroll
    for (int i = 0; i < 2; ++i)
#pragma unroll
        for (int j = 0; j < 4; ++j) acc[i][j] = f32x4{0.f, 0.f, 0.f, 0.f};

    const int total = nk1 + nk2;
    for (int it = 0; it < total; ++it) {
        const bool h2 = it >= nk1;
        const u16* A = h2 ? A2 : A1;
        const u16* W = h2 ? W2 : W1;
        const int lda = h2 ? lda2 : lda1, ldw = h2 ? ldw2 : ldw1;
        const int k0 = (h2 ? it - nk1 : it) * 128;
        __syncthreads();
#pragma unroll
        for (int g = 0; g < 4; ++g) {      // A: 64 x 128 (1024 granules)
            int ch = tid + g * 256, r = ch >> 4, cl = (ch & 15) * 8;
            *(float4*)(ldsA + r * 136 + cl) = *(const float4*)(A + (row0 + r) * lda + k0 + cl);
        }
#pragma unroll
        for (int g = 0; g < 8; ++g) {      // B: 128 gate-cols x 128 (2048 granules)
            int ch = tid + g * 256, m = ch >> 4, cl = (ch & 15) * 8;
            int wrow = (m >> 5) * 512 + j0 + (m & 31);   // gate (m>>5), j (m&31)
            *(float4*)(ldsB + m * 136 + cl) = *(const float4*)(W + wrow * ldw + k0 + cl);
        }
        __syncthreads();
#pragma unroll
        for (int ks = 0; ks < 4; ++ks) {
            const int kk = ks * 32 + q * 8;
            bh8 afr[2];
#pragma unroll
            for (int rt = 0; rt < 2; ++rt)
                afr[rt] = *(const bh8*)(ldsA + (wr * 32 + rt * 16 + ln) * 136 + kk);
#pragma unroll
            for (int nt = 0; nt < 4; ++nt) {
                bh8 bfr = *(const bh8*)(ldsB + (wc * 64 + nt * 16 + ln) * 136 + kk);
#pragma unroll
                for (int rt = 0; rt < 2; ++rt)
                    acc[rt][nt] = __builtin_amdgcn_mfma_f32_16x16x32_bf16(afr[rt], bfr, acc[rt][nt], 0, 0, 0);
            }
        }
    }
    __syncthreads();
    // C/D layout (measured m89/m91): col = lane&15, row = (lane>>4)*4 + reg
#pragma unroll
    for (int rt = 0; rt < 2; ++rt)
#pragma unroll
        for (int nt = 0; nt < 4; ++nt)
#pragma unroll
            for (int r = 0; r < 4; ++r) {
                int lrow = wr * 32 + rt * 16 + q * 4 + r;
                int lcol = wc * 64 + nt * 16 + ln;
                gbuf[lrow * 132 + lcol] = acc[rt][nt][r];
            }
    __syncthreads();
#pragma unroll
    for (int p = 0; p < 8; ++p) {
        int idx = p * 256 + tid;                 // 2048 items: 64 rows x 32 j
        int bl = idx >> 5, j = idx & 31;
        int bg = row0 + bl, jg = j0 + j;
        float gi = gbuf[bl * 132 +  0 + j] + bias[jg];
        float gf = gbuf[bl * 132 + 32 + j] + bias[512 + jg];
        float gg = gbuf[bl * 132 + 64 + j] + bias[1024 + jg];
        float go = gbuf[bl * 132 + 96 + j] + bias[1536 + jg];
        if (w0col) {
            float sv = s[bg];
            gi += sv * w0col[jg];         gf += sv * w0col[512 + jg];
            gg += sv * w0col[1024 + jg];  go += sv * w0col[1536 + jg];
        }
        float cold = b2f(c[bg * 512 + jg]);
        float cn = sigf(gf) * cold + sigf(gi) * tanh_(gg);
        float hn = sigf(go) * tanh_(cn);
        c[bg * 512 + jg] = f2b(cn);
        hout[bg * 512 + jg] = f2b(hn);
    }
    __syncthreads();
}

// f-net tile (proven): 16 rows, pred+f1+f2+f3+update. LDS 59904 B.
__device__ __forceinline__ void fnet_tile(
    char* smem, int t, int row0,
    const u16* __restrict__ h1n, const u16* __restrict__ fW1t, const float* __restrict__ fw1r0,
    const float* __restrict__ fb1, const u16* __restrict__ fW2t, const float* __restrict__ fb2,
    const float* __restrict__ fW3, const float* __restrict__ fb3,
    const float* __restrict__ cW1, const float* __restrict__ cb1,
    const float* __restrict__ cW2, const float* __restrict__ cb2,
    const float* __restrict__ Ee, const float* __restrict__ ratep,
    float* __restrict__ sp, float* __restrict__ out)
{
    u16*   ldsA  = (u16*)smem;                 // [16*64]   2048 B
    u16*   ldsB  = (u16*)(smem + 2048);        // [256*64]  32768 B
    u16*   f1buf = (u16*)(smem + 34816);       // [16*264]  8448 B
    float* f2buf = (float*)(smem + 43264);     // [16*256]  16384 B
    float* predb = (float*)(smem + 59648);     // [16]

    const int tid = threadIdx.x, wid = tid >> 6, lane = tid & 63;
    const int q = lane >> 4, ln = lane & 15;

    // phase 0: pred/gen/bp
#pragma unroll
    for (int pass = 0; pass < 2; ++pass) {
        int rl = wid * 4 + pass * 2 + (lane >> 5);
        int l = lane & 31;
        int bg = row0 + rl;
        float sv = sp[bg], Ev = Ee[bg];
        float z = sv * cW1[l] + Ev * cW1[32 + l] + cb1[l];
        float tv = tanh_(z) * cW2[l];
        tv += __shfl_xor(tv, 1); tv += __shfl_xor(tv, 2); tv += __shfl_xor(tv, 4);
        tv += __shfl_xor(tv, 8); tv += __shfl_xor(tv, 16);
        float gen = ratep[bg] * (1.f - sv);
        float pred = sv + gen + tv + cb2[0];
        if (l == 0) {
            predb[rl] = pred;
            out[OFF_GENS + bg * 32 + t] = gen;
            out[OFF_BPS + bg * 32 + t] = sigf(10.f * (pred - 0.5f));
        }
    }

    // phase 1: f1 = gelu(pred*fw1r0 + h1@fW1t^T + fb1), K=512
    f32x4 acc1[4];
#pragma unroll
    for (int b = 0; b < 4; b++) acc1[b] = f32x4{0.f, 0.f, 0.f, 0.f};
    for (int kc = 0; kc < 8; ++kc) {
        const int k0 = kc * 64;
        __syncthreads();
        if (tid < 128) {
            int r = tid >> 3, cl = (tid & 7) * 8;
            *(float4*)(ldsA + r * 64 + cl) = *(const float4*)(h1n + (row0 + r) * 512 + k0 + cl);
        }
#pragma unroll
        for (int it = 0; it < 8; ++it) {
            int chn = tid + it * 256, m = chn >> 3, cl = (chn & 7) * 8;
            *(float4*)(ldsB + m * 64 + cl) = *(const float4*)(fW1t + m * 512 + k0 + cl);
        }
        __syncthreads();
#pragma unroll
        for (int ks = 0; ks < 2; ++ks) {
            const int kk = ks * 32 + q * 8;
            bh8 a = *(const bh8*)(ldsA + ln * 64 + kk);
#pragma unroll
            for (int nt = 0; nt < 4; ++nt) {
                bh8 b = *(const bh8*)(ldsB + (wid * 64 + nt * 16 + ln) * 64 + kk);
                acc1[nt] = __builtin_amdgcn_mfma_f32_16x16x32_bf16(a, b, acc1[nt], 0, 0, 0);
            }
        }
    }
    __syncthreads();
#pragma unroll
    for (int nt = 0; nt < 4; ++nt)
#pragma unroll
        for (int r = 0; r < 4; ++r) {
            int row = q * 4 + r;
            int col = wid * 64 + nt * 16 + ln;
            float x = acc1[nt][r] + fb1[col] + predb[row] * fw1r0[col];
            f1buf[row * 264 + col] = f2b(gelu_(x));
        }

    // phase 2: f2 = gelu(f1@fW2t^T + fb2), K=256
    f32x4 acc2[4];
#pragma unroll
    for (int b = 0; b < 4; b++) acc2[b] = f32x4{0.f, 0.f, 0.f, 0.f};
    for (int kc = 0; kc < 4; ++kc) {
        const int k0 = kc * 64;
        __syncthreads();
#pragma unroll
        for (int it = 0; it < 8; ++it) {
            int chn = tid + it * 256, m = chn >> 3, cl = (chn & 7) * 8;
            *(float4*)(ldsB + m * 64 + cl) = *(const float4*)(fW2t + m * 256 + k0 + cl);
        }
        __syncthreads();
#pragma unroll
        for (int ks = 0; ks < 2; ++ks) {
            const int kk = ks * 32 + q * 8;
            bh8 a = *(const bh8*)(f1buf + ln * 264 + k0 + kk);
#pragma unroll
            for (int nt = 0; nt < 4; ++nt) {
                bh8 b = *(const bh8*)(ldsB + (wid * 64 + nt * 16 + ln) * 64 + kk);
                acc2[nt] = __builtin_amdgcn_mfma_f32_16x16x32_bf16(a, b, acc2[nt], 0, 0, 0);
            }
        }
    }
#pragma unroll
    for (int nt = 0; nt < 4; ++nt)
#pragma unroll
        for (int r = 0; r < 4; ++r) {
            int row = q * 4 + r;
            int col = wid * 64 + nt * 16 + ln;
            f2buf[row * 256 + col] = gelu_(acc2[nt][r] + fb2[col]);
        }
    __syncthreads();

    // phase 3: nxt = clip(max(s, f2@fW3 + fb3), 0, 1)
#pragma unroll
    for (int rr = 0; rr < 4; ++rr) {
        int row = wid * 4 + rr;
        f32x4 v = *(const f32x4*)(f2buf + row * 256 + lane * 4);
        float p = v[0] * fW3[lane * 4 + 0] + v[1] * fW3[lane * 4 + 1]
                + v[2] * fW3[lane * 4 + 2] + v[3] * fW3[lane * 4 + 3];
        p += __shfl_xor(p, 1); p += __shfl_xor(p, 2); p += __shfl_xor(p, 4);
        p += __shfl_xor(p, 8); p += __shfl_xor(p, 16); p += __shfl_xor(p, 32);
        if (lane == 0) {
            int bg = row0 + row;
            float nxt = p + fb3[0];
            float sv = sp[bg];
            nxt = fminf(fmaxf(fmaxf(sv, nxt), 0.f), 1.f);
            sp[bg] = nxt;
            out[bg * 32 + t] = nxt;
        }
    }
    __syncthreads();
}

// ---------------------------------------------------------------------------
// Persistent cooperative kernel: 256 blocks x 256 threads (1 block/CU under
// even the most pessimistic occupancy validation). LDS 59904 B.
// ---------------------------------------------------------------------------
struct PArgs {
    const u16 *latb, *Wp, *whh0b, *wih1b, *whh1b, *fW1t, *fW2t;
    const float *w0col, *b0, *b1, *fw1r0, *fb1, *fb2, *fW3, *fb3;
    const float *cW1, *cb1, *cW2, *cb2, *Ee, *ratep;
    float *sp;
    u16 *h0, *h1, *c0, *c1;
    float *out;
};

__global__ __launch_bounds__(256) void k_persist(PArgs a) {
    __shared__ __attribute__((aligned(16))) char smem[59904];
    cg::grid_group grid = cg::this_grid();
    const int blk = blockIdx.x;                  // 0..255
    const int j0 = (blk & 15) * 32;              // 16 j-tiles of 32
    const int row0 = (blk >> 4) * 64;            // 16 row-tiles of 64

    for (int t = 0; t < 32; ++t) {
        const int cur = t & 1, nx = cur ^ 1;
        // phase 1: lstm0 = h0@W_hh0^T (K=512) + lat@Wp^T (K=256) + s*w0col + b0
        lstm_tile64(smem, j0, row0,
                    a.h0 + cur * HS, 512, 4, a.whh0b, 512,
                    a.latb, 256, 2, a.Wp, 256,
                    a.w0col, a.sp, a.b0, a.c0, a.h0 + nx * HS);
        __threadfence(); grid.sync();
        // phase 2: lstm1 = h0n@W_ih1^T + h1@W_hh1^T + b1
        lstm_tile64(smem, j0, row0,
                    a.h0 + nx * HS, 512, 4, a.wih1b, 512,
                    a.h1 + cur * HS, 512, 4, a.whh1b, 512,
                    (const float*)nullptr, (const float*)nullptr, a.b1,
                    a.c1, a.h1 + nx * HS);
        __threadfence(); grid.sync();
        // phase 3: fused f-net + state update (blocks 0..63)
        if (blk < 64)
            fnet_tile(smem, t, blk * 16,
                      a.h1 + nx * HS, a.fW1t, a.fw1r0, a.fb1, a.fW2t, a.fb2,
                      a.fW3, a.fb3, a.cW1, a.cb1, a.cW2, a.cb2,
                      a.Ee, a.ratep, a.sp, a.out);
        __threadfence(); grid.sync();
    }
}

// ===========================================================================
// Fallback path kernels (R9, proven) — used only if cooperative launch fails
// ===========================================================================
__global__ __launch_bounds__(256) void k_lstm_m(
    const u16* __restrict__ A1, int lda1, int nk1, const void* __restrict__ W1, int ldw1, int w1f,
    const void* __restrict__ A2, int a2f, int lda2, int nk2, const void* __restrict__ W2, int ldw2, int w2f,
    const float* __restrict__ w0col, const float* __restrict__ s, const float* __restrict__ bias,
    u16* __restrict__ c, u16* __restrict__ hout)
{
    __shared__ __attribute__((aligned(16))) char smem[26112];
    u16*   ldsA = (u16*)smem;
    u16*   ldsB = (u16*)(smem + 8704);
    float* gbuf = (float*)smem;

    const int tid = threadIdx.x, wid = tid >> 6, lane = tid & 63;
    const int q = lane >> 4, ln = lane & 15;
    const int wr = wid >> 1, wc = wid & 1;
    const int j0 = blockIdx.x * 16, row0 = blockIdx.y * 32;

    f32x4 acc[2];
    acc[0] = f32x4{0.f, 0.f, 0.f, 0.f};
    acc[1] = f32x4{0.f, 0.f, 0.f, 0.f};

    const int total = nk1 + nk2;
    for (int it = 0; it < total; ++it) {
        const bool h2 = it >= nk1;
        const void* A = h2 ? A2 : (const void*)A1;
        const void* W = h2 ? W2 : W1;
        const int lda = h2 ? lda2 : lda1, ldw = h2 ? ldw2 : ldw1;
        const int af = h2 ? a2f : 0;
        const int wf = h2 ? w2f : w1f;
        const int k0 = (h2 ? it - nk1 : it) * 128;
        __syncthreads();
#pragma unroll
        for (int g = 0; g < 2; ++g) {
            int ch = tid + g * 256, r = ch >> 4, cl = (ch & 15) * 8;
            stage8(ldsA + r * 136 + cl, A, (row0 + r) * lda + k0 + cl, af);
        }
#pragma unroll
        for (int g = 0; g < 4; ++g) {
            int ch = tid + g * 256, m = ch >> 4, cl = (ch & 15) * 8;
            int wrow = (m >> 4) * 512 + j0 + (m & 15);
            stage8(ldsB + m * 136 + cl, W, wrow * ldw + k0 + cl, wf);
        }
        __syncthreads();
#pragma unroll
        for (int ks = 0; ks < 4; ++ks) {
            const int kk = ks * 32 + q * 8;
            bh8 afr = *(const bh8*)(ldsA + (wr * 16 + ln) * 136 + kk);
#pragma unroll
            for (int nt = 0; nt < 2; ++nt) {
                bh8 bfr = *(const bh8*)(ldsB + (wc * 32 + nt * 16 + ln) * 136 + kk);
                acc[nt] = __builtin_amdgcn_mfma_f32_16x16x32_bf16(afr, bfr, acc[nt], 0, 0, 0);
            }
        }
    }
    __syncthreads();
#pragma unroll
    for (int nt = 0; nt < 2; ++nt)
#pragma unroll
        for (int r = 0; r < 4; ++r) {
            int lrow = wr * 16 + q * 4 + r;
            int lcol = wc * 32 + nt * 16 + ln;
            gbuf[lrow * 68 + lcol] = acc[nt][r];
        }
    __syncthreads();
#pragma unroll
    for (int p = 0; p < 2; ++p) {
        int idx = p * 256 + tid;
        int bl = idx >> 4, j = idx & 15;
        int bg = row0 + bl, jg = j0 + j;
        float gi = gbuf[bl * 68 +  0 + j] + bias[jg];
        float gf = gbuf[bl * 68 + 16 + j] + bias[512 + jg];
        float gg = gbuf[bl * 68 + 32 + j] + bias[1024 + jg];
        float go = gbuf[bl * 68 + 48 + j] + bias[1536 + jg];
        if (w0col) {
            float sv = s[bg];
            gi += sv * w0col[jg];         gf += sv * w0col[512 + jg];
            gg += sv * w0col[1024 + jg];  go += sv * w0col[1536 + jg];
        }
        float cold = b2f(c[bg * 512 + jg]);
        float cn = sigf(gf) * cold + sigf(gi) * tanh_(gg);
        float hn = sigf(go) * tanh_(cn);
        c[bg * 512 + jg] = f2b(cn);
        hout[bg * 512 + jg] = f2b(hn);
    }
}

__global__ __launch_bounds__(256) void k_fnet(
    int t,
    const u16* __restrict__ h1n, const u16* __restrict__ fW1t, const float* __restrict__ fw1r0,
    const float* __restrict__ fb1, const u16* __restrict__ fW2t, const float* __restrict__ fb2,
    const float* __restrict__ fW3, const float* __restrict__ fb3,
    const float* __restrict__ cW1, const float* __restrict__ cb1,
    const float* __restrict__ cW2, const float* __restrict__ cb2,
    const float* __restrict__ Ee, const float* __restrict__ ratep,
    float* __restrict__ sp, float* __restrict__ out)
{
    __shared__ __attribute__((aligned(16))) char smem[59904];
    fnet_tile(smem, t, blockIdx.x * 16, h1n, fW1t, fw1r0, fb1, fW2t, fb2,
              fW3, fb3, cW1, cb1, cW2, cb2, Ee, ratep, sp, out);
}

// ---------------------------------------------------------------------------
extern "C" void kernel_launch(void* const* d_in, const int* in_sizes, int n_in,
                              void* d_out, int out_size, void* d_ws, size_t ws_size,
                              hipStream_t stream) {
    const float* ist   = (const float*)d_in[0];
    const float* lat   = (const float*)d_in[1];
    const float* vol   = (const float*)d_in[2];
    const float* thick = (const float*)d_in[3];
    const float* trap  = (const float*)d_in[4];
    const float* W_ih0 = (const float*)d_in[5];
    const float* W_hh0 = (const float*)d_in[6];
    const float* b0_   = (const float*)d_in[7];
    const float* W_ih1 = (const float*)d_in[8];
    const float* W_hh1 = (const float*)d_in[9];
    const float* b1_   = (const float*)d_in[10];
    const float* fW1   = (const float*)d_in[11];
    const float* fb1   = (const float*)d_in[12];
    const float* fW2   = (const float*)d_in[13];
    const float* fb2   = (const float*)d_in[14];
    const float* fW3   = (const float*)d_in[15];
    const float* fb3   = (const float*)d_in[16];
    const float* cW1   = (const float*)d_in[17];
    const float* cb1   = (const float*)d_in[18];
    const float* cW2   = (const float*)d_in[19];
    const float* cb2   = (const float*)d_in[20];

    char* ws = (char*)d_ws;
    u16*   Wp    = (u16*)(ws + WS_WP);
    u16*   fW1t  = (u16*)(ws + WS_FW1T);
    u16*   fW2t  = (u16*)(ws + WS_FW2T);
    float* fw1r0 = (float*)(ws + WS_FW1R0);
    float* w0col = (float*)(ws + WS_W0COL);
    float* Ee    = (float*)(ws + WS_EE);
    float* ratep = (float*)(ws + WS_RATE);
    float* sp    = (float*)(ws + WS_SP);
    u16*   h0    = (u16*)(ws + WS_H0);
    u16*   h1    = (u16*)(ws + WS_H1);
    u16*   c0    = (u16*)(ws + WS_C0);
    u16*   c1    = (u16*)(ws + WS_C1);
    u16*   wih1b = (u16*)(ws + WS_WIH1B);
    u16*   whh1b = (u16*)(ws + WS_WHH1B);
    u16*   whh0b = (u16*)(ws + WS_WHH0B);
    u16*   latb  = (u16*)(ws + WS_LATB);
    float* out   = (float*)d_out;

    const bool coop = ws_size >= (size_t)WS_T3_END;
    const bool t1 = ws_size >= (size_t)WS_T1_END;
    const bool t2 = ws_size >= (size_t)WS_T2_END;

    k_setup<<<2048, 256, 0, stream>>>(ist, lat, vol, thick, trap, W_ih0, fW1, fW2,
        h0, h1, c0, c1, Wp, w0col, fW1t, fW2t, fw1r0,
        coop ? latb : (u16*)nullptr, Ee, ratep, sp, out + OFF_E);

    if (t2) k_conv3w<<<12288, 256, 0, stream>>>(W_ih1, W_hh1, W_hh0, wih1b, whh1b, whh0b);
    else if (t1) k_conv3w<<<12288, 256, 0, stream>>>(W_ih1, W_hh1, W_hh1, wih1b, whh1b, whh1b);

    if (coop && t2) {
        PArgs pa;
        pa.latb = latb; pa.Wp = Wp; pa.whh0b = whh0b; pa.wih1b = wih1b; pa.whh1b = whh1b;
        pa.fW1t = fW1t; pa.fW2t = fW2t;
        pa.w0col = w0col; pa.b0 = b0_; pa.b1 = b1_; pa.fw1r0 = fw1r0;
        pa.fb1 = fb1; pa.fb2 = fb2; pa.fW3 = fW3; pa.fb3 = fb3;
        pa.cW1 = cW1; pa.cb1 = cb1; pa.cW2 = cW2; pa.cb2 = cb2;
        pa.Ee = Ee; pa.ratep = ratep; pa.sp = sp;
        pa.h0 = h0; pa.h1 = h1; pa.c0 = c0; pa.c1 = c1; pa.out = out;
        void* kargs[] = { &pa };
        hipError_t err = hipLaunchCooperativeKernel((const void*)k_persist, dim3(256), dim3(256),
                                                    kargs, 0, stream);
        if (err == hipSuccess) return;
        // cooperative launch rejected -> fall through to multi-launch path
        (void)hipGetLastError();   // clear sticky error
    }

    // fallback: R9 multi-launch path
    const void* pWhh0 = t2 ? (const void*)whh0b : (const void*)W_hh0;
    const void* pWih1 = t1 ? (const void*)wih1b : (const void*)W_ih1;
    const void* pWhh1 = t1 ? (const void*)whh1b : (const void*)W_hh1;
    const int wf0 = t2 ? 0 : 1;
    const int wf1 = t1 ? 0 : 1;

    for (int t = 0; t < 32; ++t) {
        int cur = t & 1, nx = cur ^ 1;
        k_lstm_m<<<dim3(32, 32), 256, 0, stream>>>(
            h0 + cur * HS, 512, 4, pWhh0, 512, wf0,
            lat, 1, 256, 2, Wp, 256, 0,
            w0col, sp, b0_, c0, h0 + nx * HS);
        k_lstm_m<<<dim3(32, 32), 256, 0, stream>>>(
            h0 + nx * HS, 512, 4, pWih1, 512, wf1,
            h1 + cur * HS, 0, 512, 4, pWhh1, 512, wf1,
            (const float*)nullptr, (const float*)nullptr, b1_, c1, h1 + nx * HS);
        k_fnet<<<64, 256, 0, stream>>>(t, h1 + nx * HS, fW1t, fw1r0, fb1, fW2t, fb2,
            fW3, fb3, cW1, cb1, cW2, cb2, Ee, ratep, sp, out);
    }
}

// Round 12
// 2324.890 us; speedup vs baseline: 3.5567x; 3.5567x over previous
//
#include <hip/hip_runtime.h>
#include <hip/hip_bf16.h>

typedef unsigned short u16;
typedef unsigned int u32;
typedef __attribute__((ext_vector_type(8))) short bh8;     // 8 x bf16 MFMA A/B frag
typedef __attribute__((ext_vector_type(4))) float f32x4;   // MFMA C/D frag

#define KB_T 0.025851f
#define HS (1024 * 512)

// d_out (fp32): preds.T [1024][32] | E [1024] | gens.T [1024][32] | bps.T [1024][32]
#define OFF_E    32768
#define OFF_GENS 33792
#define OFF_BPS  66560

// ---- workspace layout (byte offsets)
#define WS_WP     0u         // [2048][256] bf16  (W_ih0[:,1:])
#define WS_FW1T   1048576u   // [256][512] bf16   (fW1[1:] ^T)
#define WS_FW2T   1310720u   // [256][256] bf16   (fW2 ^T)
#define WS_FW1R0  1441792u   // [256] f32         (fW1 row 0)
#define WS_W0COL  1442816u   // [2048] f32        (W_ih0[:,0])
#define WS_EE     1451008u   // [1024] f32
#define WS_RATE   1455104u   // [1024] f32
#define WS_SP     1459200u   // [1024] f32
#define WS_H0     1463296u   // 2x[1024][512] bf16 ping-pong
#define WS_H1     3560448u   // 2x[1024][512] bf16
#define WS_C0     5657600u   // [1024][512] bf16
#define WS_C1     6706176u   // [1024][512] bf16
#define WS_BASE_END 7754752u
// tier1 (ws >= 11949056): bf16 W_ih1 + W_hh1. tier2 (ws >= 14046208): + W_hh0
#define WS_WIH1B  7754752u
#define WS_WHH1B  9851904u
#define WS_T1_END 11949056u
#define WS_WHH0B  11949056u
#define WS_T2_END 14046208u

__device__ __forceinline__ float b2f(u16 u) { u32 x = ((u32)u) << 16; float f; __builtin_memcpy(&f, &x, 4); return f; }
__device__ __forceinline__ u16 f2b(float f) { __hip_bfloat16 h = __float2bfloat16(f); u16 u; __builtin_memcpy(&u, &h, 2); return u; }
__device__ __forceinline__ float sigf(float x) { return 1.f / (1.f + __expf(-x)); }
__device__ __forceinline__ float tanh_(float x) { return 1.f - 2.f / (__expf(2.f * x) + 1.f); }
__device__ __forceinline__ float gelu_(float x) { return 0.5f * x * (1.f + tanh_(0.7978845608f * (x + 0.044715f * x * x * x))); }

// stage 8 contiguous elements into LDS as bf16; src bf16 (16B copy) or fp32 (32B + cvt)
__device__ __forceinline__ void stage8(u16* dst, const void* src, int ofs, int srcf32) {
    if (srcf32) {
        const float* s = (const float*)src + ofs;
        float4 a = *(const float4*)s;
        float4 b = *(const float4*)(s + 4);
        u16 t[8] = {f2b(a.x), f2b(a.y), f2b(a.z), f2b(a.w),
                    f2b(b.x), f2b(b.y), f2b(b.z), f2b(b.w)};
        *(float4*)dst = *(const float4*)t;
    } else {
        *(float4*)dst = *(const float4*)((const u16*)src + ofs);
    }
}

// ---------------------------------------------------------------------------
// setup (proven): zero states; repack W_ih0 -> Wp+w0col; fW1 -> fW1t+fw1r0;
// fW2 -> fW2t; E/rate/s0. grid 2048 x 256.
// ---------------------------------------------------------------------------
__global__ __launch_bounds__(256) void k_setup(
    const float* __restrict__ ist, const float* __restrict__ vol, const float* __restrict__ thick,
    const float* __restrict__ trap, const float* __restrict__ W_ih0,
    const float* __restrict__ fW1, const float* __restrict__ fW2,
    u16* __restrict__ h0, u16* __restrict__ h1, u16* __restrict__ c0, u16* __restrict__ c1,
    u16* __restrict__ Wp, float* __restrict__ w0col,
    u16* __restrict__ fW1t, u16* __restrict__ fW2t, float* __restrict__ fw1r0,
    float* __restrict__ Ee, float* __restrict__ ratep, float* __restrict__ sp,
    float* __restrict__ outE)
{
    const int idx = blockIdx.x * 256 + threadIdx.x;
    h0[idx] = 0; h1[idx] = 0; c0[idx] = 0; c1[idx] = 0;
    Wp[idx] = f2b(W_ih0[(idx >> 8) * 257 + 1 + (idx & 255)]);
    if (idx < 131072) { int n = idx >> 9, k = idx & 511; fW1t[n * 512 + k] = f2b(fW1[(1 + k) * 256 + n]); }
    if (idx < 65536)  { int n = idx >> 8, k = idx & 255; fW2t[n * 256 + k] = f2b(fW2[k * 256 + n]); }
    if (idx < 2048)   w0col[idx] = W_ih0[idx * 257];
    if (idx < 256)    fw1r0[idx] = fW1[idx];
    if (idx < 1024) {
        float E = vol[idx] / thick[idx];
        float Ea = trap[idx * 8], ga = trap[idx * 8 + 1];
        ratep[idx] = __expf(-fmaxf(Ea - ga * E, 0.f) / KB_T);
        Ee[idx] = E;
        sp[idx] = ist[idx * 10 + 9];
        outE[idx] = E;
    }
}

// fp32 -> bf16 convert of three [2048][512] weights in one launch. grid 12288 x 256.
__global__ __launch_bounds__(256) void k_conv3w(
    const float* __restrict__ a, const float* __restrict__ b, const float* __restrict__ c,
    u16* __restrict__ oa, u16* __restrict__ ob, u16* __restrict__ oc)
{
    const int idx = blockIdx.x * 256 + threadIdx.x;   // [0, 3145728)
    const int w = idx >> 20, i = idx & 1048575;
    if (w == 0)      oa[i] = f2b(a[i]);
    else if (w == 1) ob[i] = f2b(b[i]);
    else             oc[i] = f2b(c[i]);
}

// ---------------------------------------------------------------------------
// MFMA LSTM cell v4. gates = bias + A1@W1^T + A2@W2^T [+ s*w0col].
// Tile 64 rows x 64 gate-cols (4 gates x 16 j), BK=128.
// grid dim3(32, 16) = 512 blocks -> 2 blocks/CU (LDS 34816 B, 8 waves/CU).
// Waves 2x2, each 32 rows x 32 gate-cols: 16 MFMA per wave per K-chunk.
// LDS rows padded to 136 u16. gbuf[64][68] f32 overlays ldsA (post-barrier).
// ---------------------------------------------------------------------------
__global__ __launch_bounds__(256, 2) void k_lstm_m(
    const u16* __restrict__ A1, int lda1, int nk1, const void* __restrict__ W1, int ldw1, int w1f,
    const void* __restrict__ A2, int a2f, int lda2, int nk2, const void* __restrict__ W2, int ldw2, int w2f,
    const float* __restrict__ w0col, const float* __restrict__ s, const float* __restrict__ bias,
    u16* __restrict__ c, u16* __restrict__ hout)
{
    __shared__ __attribute__((aligned(16))) char smem[34816];
    u16*   ldsA = (u16*)smem;                // [64][136] u16, 17408 B
    u16*   ldsB = (u16*)(smem + 17408);      // [64][136] u16, 17408 B
    float* gbuf = (float*)smem;              // [64][68] f32, 17408 B (post-barrier overlay)

    const int tid = threadIdx.x, wid = tid >> 6, lane = tid & 63;
    const int q = lane >> 4, ln = lane & 15;
    const int wr = wid >> 1, wc = wid & 1;           // wave = 32 rows x 32 gate-cols
    const int j0 = blockIdx.x * 16, row0 = blockIdx.y * 64;

    f32x4 acc[2][2];
#pragma unroll
    for (int i = 0; i < 2; ++i)
#pragma unroll
        for (int j = 0; j < 2; ++j) acc[i][j] = f32x4{0.f, 0.f, 0.f, 0.f};

    const int total = nk1 + nk2;
    for (int it = 0; it < total; ++it) {
        const bool h2 = it >= nk1;
        const void* A = h2 ? A2 : (const void*)A1;
        const void* W = h2 ? W2 : W1;
        const int lda = h2 ? lda2 : lda1, ldw = h2 ? ldw2 : ldw1;
        const int af = h2 ? a2f : 0;
        const int wf = h2 ? w2f : w1f;
        const int k0 = (h2 ? it - nk1 : it) * 128;
        __syncthreads();
#pragma unroll
        for (int g = 0; g < 4; ++g) {      // ldsA: 64 rows x 128 k (1024 granules)
            int ch = tid + g * 256, r = ch >> 4, cl = (ch & 15) * 8;
            stage8(ldsA + r * 136 + cl, A, (row0 + r) * lda + k0 + cl, af);
        }
#pragma unroll
        for (int g = 0; g < 4; ++g) {      // ldsB: 64 gate-cols x 128 k (1024 granules)
            int ch = tid + g * 256, m = ch >> 4, cl = (ch & 15) * 8;
            int wrow = (m >> 4) * 512 + j0 + (m & 15);   // gate (m>>4), col j (m&15)
            stage8(ldsB + m * 136 + cl, W, wrow * ldw + k0 + cl, wf);
        }
        __syncthreads();
#pragma unroll
        for (int ks = 0; ks < 4; ++ks) {
            const int kk = ks * 32 + q * 8;
            bh8 afr[2];
#pragma unroll
            for (int rt = 0; rt < 2; ++rt)
                afr[rt] = *(const bh8*)(ldsA + (wr * 32 + rt * 16 + ln) * 136 + kk);
#pragma unroll
            for (int nt = 0; nt < 2; ++nt) {
                bh8 bfr = *(const bh8*)(ldsB + (wc * 32 + nt * 16 + ln) * 136 + kk);
#pragma unroll
                for (int rt = 0; rt < 2; ++rt)
                    acc[rt][nt] = __builtin_amdgcn_mfma_f32_16x16x32_bf16(afr[rt], bfr, acc[rt][nt], 0, 0, 0);
            }
        }
    }
    __syncthreads();
    // C/D layout (measured m89/m91): col = lane&15, row = (lane>>4)*4 + reg
#pragma unroll
    for (int rt = 0; rt < 2; ++rt)
#pragma unroll
        for (int nt = 0; nt < 2; ++nt)
#pragma unroll
            for (int r = 0; r < 4; ++r) {
                int lrow = wr * 32 + rt * 16 + q * 4 + r;
                int lcol = wc * 32 + nt * 16 + ln;
                gbuf[lrow * 68 + lcol] = acc[rt][nt][r];
            }
    __syncthreads();
#pragma unroll
    for (int p = 0; p < 4; ++p) {
        int idx = p * 256 + tid;                 // 1024 items: 64 rows x 16 j
        int bl = idx >> 4, j = idx & 15;
        int bg = row0 + bl, jg = j0 + j;
        float gi = gbuf[bl * 68 +  0 + j] + bias[jg];
        float gf = gbuf[bl * 68 + 16 + j] + bias[512 + jg];
        float gg = gbuf[bl * 68 + 32 + j] + bias[1024 + jg];
        float go = gbuf[bl * 68 + 48 + j] + bias[1536 + jg];
        if (w0col) {
            float sv = s[bg];
            gi += sv * w0col[jg];         gf += sv * w0col[512 + jg];
            gg += sv * w0col[1024 + jg];  go += sv * w0col[1536 + jg];
        }
        float cold = b2f(c[bg * 512 + jg]);
        float cn = sigf(gf) * cold + sigf(gi) * tanh_(gg);
        float hn = sigf(go) * tanh_(cn);
        c[bg * 512 + jg] = f2b(cn);
        hout[bg * 512 + jg] = f2b(hn);
    }
}

// ---------------------------------------------------------------------------
// Fused f-net (proven R8/R9): pred/gen/bp + f1(MFMA) + f2(MFMA) + f3 + update.
// 16 rows/WG, 64 WGs, 256 threads. f1buf padded to 264.
// ---------------------------------------------------------------------------
__global__ __launch_bounds__(256) void k_fnet(
    int t,
    const u16* __restrict__ h1n, const u16* __restrict__ fW1t, const float* __restrict__ fw1r0,
    const float* __restrict__ fb1, const u16* __restrict__ fW2t, const float* __restrict__ fb2,
    const float* __restrict__ fW3, const float* __restrict__ fb3,
    const float* __restrict__ cW1, const float* __restrict__ cb1,
    const float* __restrict__ cW2, const float* __restrict__ cb2,
    const float* __restrict__ Ee, const float* __restrict__ ratep,
    float* __restrict__ sp, float* __restrict__ out)
{
    __shared__ __attribute__((aligned(16))) u16 ldsA[16 * 64];     // 2KB
    __shared__ __attribute__((aligned(16))) u16 ldsB[256 * 64];    // 32KB
    __shared__ __attribute__((aligned(16))) u16 f1buf[16 * 264];   // 8.25KB (padded)
    __shared__ __attribute__((aligned(16))) float f2buf[16 * 256]; // 16KB
    __shared__ float predb[16];

    const int tid = threadIdx.x, wid = tid >> 6, lane = tid & 63;
    const int q = lane >> 4, ln = lane & 15;
    const int row0 = blockIdx.x * 16;

    // phase 0: pred/gen/bp
#pragma unroll
    for (int pass = 0; pass < 2; ++pass) {
        int rl = wid * 4 + pass * 2 + (lane >> 5);
        int l = lane & 31;
        int bg = row0 + rl;
        float sv = sp[bg], Ev = Ee[bg];
        float z = sv * cW1[l] + Ev * cW1[32 + l] + cb1[l];
        float tv = tanh_(z) * cW2[l];
        tv += __shfl_xor(tv, 1); tv += __shfl_xor(tv, 2); tv += __shfl_xor(tv, 4);
        tv += __shfl_xor(tv, 8); tv += __shfl_xor(tv, 16);
        float gen = ratep[bg] * (1.f - sv);
        float pred = sv + gen + tv + cb2[0];
        if (l == 0) {
            predb[rl] = pred;
            out[OFF_GENS + bg * 32 + t] = gen;
            out[OFF_BPS + bg * 32 + t] = sigf(10.f * (pred - 0.5f));
        }
    }

    // phase 1: f1 = gelu(pred*fw1r0 + h1@fW1t^T + fb1), K=512
    f32x4 acc1[4];
#pragma unroll
    for (int b = 0; b < 4; b++) acc1[b] = f32x4{0.f, 0.f, 0.f, 0.f};
    for (int kc = 0; kc < 8; ++kc) {
        const int k0 = kc * 64;
        __syncthreads();
        if (tid < 128) {
            int r = tid >> 3, cl = (tid & 7) * 8;
            *(float4*)(ldsA + r * 64 + cl) = *(const float4*)(h1n + (row0 + r) * 512 + k0 + cl);
        }
#pragma unroll
        for (int it = 0; it < 8; ++it) {
            int chn = tid + it * 256, m = chn >> 3, cl = (chn & 7) * 8;
            *(float4*)(ldsB + m * 64 + cl) = *(const float4*)(fW1t + m * 512 + k0 + cl);
        }
        __syncthreads();
#pragma unroll
        for (int ks = 0; ks < 2; ++ks) {
            const int kk = ks * 32 + q * 8;
            bh8 a = *(const bh8*)(ldsA + ln * 64 + kk);
#pragma unroll
            for (int nt = 0; nt < 4; ++nt) {
                bh8 b = *(const bh8*)(ldsB + (wid * 64 + nt * 16 + ln) * 64 + kk);
                acc1[nt] = __builtin_amdgcn_mfma_f32_16x16x32_bf16(a, b, acc1[nt], 0, 0, 0);
            }
        }
    }
    __syncthreads();
#pragma unroll
    for (int nt = 0; nt < 4; ++nt)
#pragma unroll
        for (int r = 0; r < 4; ++r) {
            int row = q * 4 + r;
            int col = wid * 64 + nt * 16 + ln;
            float x = acc1[nt][r] + fb1[col] + predb[row] * fw1r0[col];
            f1buf[row * 264 + col] = f2b(gelu_(x));
        }

    // phase 2: f2 = gelu(f1@fW2t^T + fb2), K=256
    f32x4 acc2[4];
#pragma unroll
    for (int b = 0; b < 4; b++) acc2[b] = f32x4{0.f, 0.f, 0.f, 0.f};
    for (int kc = 0; kc < 4; ++kc) {
        const int k0 = kc * 64;
        __syncthreads();
#pragma unroll
        for (int it = 0; it < 8; ++it) {
            int chn = tid + it * 256, m = chn >> 3, cl = (chn & 7) * 8;
            *(float4*)(ldsB + m * 64 + cl) = *(const float4*)(fW2t + m * 256 + k0 + cl);
        }
        __syncthreads();
#pragma unroll
        for (int ks = 0; ks < 2; ++ks) {
            const int kk = ks * 32 + q * 8;
            bh8 a = *(const bh8*)(f1buf + ln * 264 + k0 + kk);
#pragma unroll
            for (int nt = 0; nt < 4; ++nt) {
                bh8 b = *(const bh8*)(ldsB + (wid * 64 + nt * 16 + ln) * 64 + kk);
                acc2[nt] = __builtin_amdgcn_mfma_f32_16x16x32_bf16(a, b, acc2[nt], 0, 0, 0);
            }
        }
    }
#pragma unroll
    for (int nt = 0; nt < 4; ++nt)
#pragma unroll
        for (int r = 0; r < 4; ++r) {
            int row = q * 4 + r;
            int col = wid * 64 + nt * 16 + ln;
            f2buf[row * 256 + col] = gelu_(acc2[nt][r] + fb2[col]);
        }
    __syncthreads();

    // phase 3: nxt = clip(max(s, f2@fW3 + fb3), 0, 1)
#pragma unroll
    for (int rr = 0; rr < 4; ++rr) {
        int row = wid * 4 + rr;
        f32x4 v = *(const f32x4*)(f2buf + row * 256 + lane * 4);
        float p = v[0] * fW3[lane * 4 + 0] + v[1] * fW3[lane * 4 + 1]
                + v[2] * fW3[lane * 4 + 2] + v[3] * fW3[lane * 4 + 3];
        p += __shfl_xor(p, 1); p += __shfl_xor(p, 2); p += __shfl_xor(p, 4);
        p += __shfl_xor(p, 8); p += __shfl_xor(p, 16); p += __shfl_xor(p, 32);
        if (lane == 0) {
            int bg = row0 + row;
            float nxt = p + fb3[0];
            float sv = sp[bg];
            nxt = fminf(fmaxf(fmaxf(sv, nxt), 0.f), 1.f);
            sp[bg] = nxt;
            out[bg * 32 + t] = nxt;
        }
    }
}

// ---------------------------------------------------------------------------
extern "C" void kernel_launch(void* const* d_in, const int* in_sizes, int n_in,
                              void* d_out, int out_size, void* d_ws, size_t ws_size,
                              hipStream_t stream) {
    const float* ist   = (const float*)d_in[0];
    const float* lat   = (const float*)d_in[1];
    const float* vol   = (const float*)d_in[2];
    const float* thick = (const float*)d_in[3];
    const float* trap  = (const float*)d_in[4];
    const float* W_ih0 = (const float*)d_in[5];
    const float* W_hh0 = (const float*)d_in[6];
    const float* b0_   = (const float*)d_in[7];
    const float* W_ih1 = (const float*)d_in[8];
    const float* W_hh1 = (const float*)d_in[9];
    const float* b1_   = (const float*)d_in[10];
    const float* fW1   = (const float*)d_in[11];
    const float* fb1   = (const float*)d_in[12];
    const float* fW2   = (const float*)d_in[13];
    const float* fb2   = (const float*)d_in[14];
    const float* fW3   = (const float*)d_in[15];
    const float* fb3   = (const float*)d_in[16];
    const float* cW1   = (const float*)d_in[17];
    const float* cb1   = (const float*)d_in[18];
    const float* cW2   = (const float*)d_in[19];
    const float* cb2   = (const float*)d_in[20];

    char* ws = (char*)d_ws;
    u16*   Wp    = (u16*)(ws + WS_WP);
    u16*   fW1t  = (u16*)(ws + WS_FW1T);
    u16*   fW2t  = (u16*)(ws + WS_FW2T);
    float* fw1r0 = (float*)(ws + WS_FW1R0);
    float* w0col = (float*)(ws + WS_W0COL);
    float* Ee    = (float*)(ws + WS_EE);
    float* ratep = (float*)(ws + WS_RATE);
    float* sp    = (float*)(ws + WS_SP);
    u16*   h0    = (u16*)(ws + WS_H0);
    u16*   h1    = (u16*)(ws + WS_H1);
    u16*   c0    = (u16*)(ws + WS_C0);
    u16*   c1    = (u16*)(ws + WS_C1);
    float* out   = (float*)d_out;

    const bool t1 = ws_size >= (size_t)WS_T1_END;   // bf16 W_ih1 + W_hh1
    const bool t2 = ws_size >= (size_t)WS_T2_END;   // + bf16 W_hh0
    u16* wih1b = (u16*)(ws + WS_WIH1B);
    u16* whh1b = (u16*)(ws + WS_WHH1B);
    u16* whh0b = (u16*)(ws + WS_WHH0B);

    k_setup<<<2048, 256, 0, stream>>>(ist, vol, thick, trap, W_ih0, fW1, fW2,
        h0, h1, c0, c1, Wp, w0col, fW1t, fW2t, fw1r0, Ee, ratep, sp, out + OFF_E);
    if (t2) {
        k_conv3w<<<12288, 256, 0, stream>>>(W_ih1, W_hh1, W_hh0, wih1b, whh1b, whh0b);
    } else if (t1) {
        k_conv3w<<<12288, 256, 0, stream>>>(W_ih1, W_hh1, W_hh1, wih1b, whh1b, whh1b);
    }

    const void* pWhh0 = t2 ? (const void*)whh0b : (const void*)W_hh0;
    const void* pWih1 = t1 ? (const void*)wih1b : (const void*)W_ih1;
    const void* pWhh1 = t1 ? (const void*)whh1b : (const void*)W_hh1;
    const int wf0 = t2 ? 0 : 1;
    const int wf1 = t1 ? 0 : 1;

    for (int t = 0; t < 32; ++t) {
        int cur = t & 1, nx = cur ^ 1;
        // lstm0: h0@W_hh0^T (K=512: nk=4) + lat@Wp^T (K=256: nk=2) + s*w0col + b0
        k_lstm_m<<<dim3(32, 16), 256, 0, stream>>>(
            h0 + cur * HS, 512, 4, pWhh0, 512, wf0,
            lat, 1, 256, 2, Wp, 256, 0,
            w0col, sp, b0_, c0, h0 + nx * HS);
        // lstm1: h0n@W_ih1^T (nk=4) + h1@W_hh1^T (nk=4) + b1
        k_lstm_m<<<dim3(32, 16), 256, 0, stream>>>(
            h0 + nx * HS, 512, 4, pWih1, 512, wf1,
            h1 + cur * HS, 0, 512, 4, pWhh1, 512, wf1,
            (const float*)nullptr, (const float*)nullptr, b1_, c1, h1 + nx * HS);
        // fused pred + f-net + state update
        k_fnet<<<64, 256, 0, stream>>>(t, h1 + nx * HS, fW1t, fw1r0, fb1, fW2t, fb2,
            fW3, fb3, cW1, cb1, cW2, cb2, Ee, ratep, sp, out);
    }
}

// Round 13
// 1913.762 us; speedup vs baseline: 4.3208x; 1.2148x over previous
//
#include <hip/hip_runtime.h>
#include <hip/hip_bf16.h>

typedef unsigned short u16;
typedef unsigned int u32;
typedef __attribute__((ext_vector_type(8))) short bh8;     // 8 x bf16 MFMA A/B frag
typedef __attribute__((ext_vector_type(4))) float f32x4;   // MFMA C/D frag

#define KB_T 0.025851f
#define HS (1024 * 512)

// d_out (fp32): preds.T [1024][32] | E [1024] | gens.T [1024][32] | bps.T [1024][32]
#define OFF_E    32768
#define OFF_GENS 33792
#define OFF_BPS  66560

// ---- workspace layout (byte offsets)
#define WS_WP     0u         // [2048][256] bf16  (W_ih0[:,1:])
#define WS_FW1T   1048576u   // [256][512] bf16   (fW1[1:] ^T)
#define WS_FW2T   1310720u   // [256][256] bf16   (fW2 ^T)
#define WS_FW1R0  1441792u   // [256] f32         (fW1 row 0)
#define WS_W0COL  1442816u   // [2048] f32        (W_ih0[:,0])
#define WS_EE     1451008u   // [1024] f32
#define WS_RATE   1455104u   // [1024] f32
#define WS_SP     1459200u   // [1024] f32
#define WS_H0     1463296u   // 2x[1024][512] bf16 ping-pong
#define WS_H1     3560448u   // 2x[1024][512] bf16
#define WS_C0     5657600u   // [1024][512] bf16
#define WS_C1     6706176u   // [1024][512] bf16
#define WS_BASE_END 7754752u
// tier1 (ws >= 11949056): bf16 W_ih1 + W_hh1. tier2 (ws >= 14046208): + W_hh0
#define WS_WIH1B  7754752u
#define WS_WHH1B  9851904u
#define WS_T1_END 11949056u
#define WS_WHH0B  11949056u
#define WS_T2_END 14046208u

__device__ __forceinline__ float b2f(u16 u) { u32 x = ((u32)u) << 16; float f; __builtin_memcpy(&f, &x, 4); return f; }
__device__ __forceinline__ u16 f2b(float f) { __hip_bfloat16 h = __float2bfloat16(f); u16 u; __builtin_memcpy(&u, &h, 2); return u; }
__device__ __forceinline__ float sigf(float x) { return 1.f / (1.f + __expf(-x)); }
__device__ __forceinline__ float tanh_(float x) { return 1.f - 2.f / (__expf(2.f * x) + 1.f); }
__device__ __forceinline__ float gelu_(float x) { return 0.5f * x * (1.f + tanh_(0.7978845608f * (x + 0.044715f * x * x * x))); }

// stage 8 contiguous elements into LDS as bf16; src bf16 (16B copy) or fp32 (32B + cvt)
__device__ __forceinline__ void stage8(u16* dst, const void* src, int ofs, int srcf32) {
    if (srcf32) {
        const float* s = (const float*)src + ofs;
        float4 a = *(const float4*)s;
        float4 b = *(const float4*)(s + 4);
        u16 t[8] = {f2b(a.x), f2b(a.y), f2b(a.z), f2b(a.w),
                    f2b(b.x), f2b(b.y), f2b(b.z), f2b(b.w)};
        *(float4*)dst = *(const float4*)t;
    } else {
        *(float4*)dst = *(const float4*)((const u16*)src + ofs);
    }
}

// ---------------------------------------------------------------------------
// setup (proven): zero states; repack W_ih0 -> Wp+w0col; fW1 -> fW1t+fw1r0;
// fW2 -> fW2t; E/rate/s0. grid 2048 x 256.
// ---------------------------------------------------------------------------
__global__ __launch_bounds__(256) void k_setup(
    const float* __restrict__ ist, const float* __restrict__ vol, const float* __restrict__ thick,
    const float* __restrict__ trap, const float* __restrict__ W_ih0,
    const float* __restrict__ fW1, const float* __restrict__ fW2,
    u16* __restrict__ h0, u16* __restrict__ h1, u16* __restrict__ c0, u16* __restrict__ c1,
    u16* __restrict__ Wp, float* __restrict__ w0col,
    u16* __restrict__ fW1t, u16* __restrict__ fW2t, float* __restrict__ fw1r0,
    float* __restrict__ Ee, float* __restrict__ ratep, float* __restrict__ sp,
    float* __restrict__ outE)
{
    const int idx = blockIdx.x * 256 + threadIdx.x;
    h0[idx] = 0; h1[idx] = 0; c0[idx] = 0; c1[idx] = 0;
    Wp[idx] = f2b(W_ih0[(idx >> 8) * 257 + 1 + (idx & 255)]);
    if (idx < 131072) { int n = idx >> 9, k = idx & 511; fW1t[n * 512 + k] = f2b(fW1[(1 + k) * 256 + n]); }
    if (idx < 65536)  { int n = idx >> 8, k = idx & 255; fW2t[n * 256 + k] = f2b(fW2[k * 256 + n]); }
    if (idx < 2048)   w0col[idx] = W_ih0[idx * 257];
    if (idx < 256)    fw1r0[idx] = fW1[idx];
    if (idx < 1024) {
        float E = vol[idx] / thick[idx];
        float Ea = trap[idx * 8], ga = trap[idx * 8 + 1];
        ratep[idx] = __expf(-fmaxf(Ea - ga * E, 0.f) / KB_T);
        Ee[idx] = E;
        sp[idx] = ist[idx * 10 + 9];
        outE[idx] = E;
    }
}

// fp32 -> bf16 convert of three [2048][512] weights in one launch. grid 12288 x 256.
__global__ __launch_bounds__(256) void k_conv3w(
    const float* __restrict__ a, const float* __restrict__ b, const float* __restrict__ c,
    u16* __restrict__ oa, u16* __restrict__ ob, u16* __restrict__ oc)
{
    const int idx = blockIdx.x * 256 + threadIdx.x;   // [0, 3145728)
    const int w = idx >> 20, i = idx & 1048575;
    if (w == 0)      oa[i] = f2b(a[i]);
    else if (w == 1) ob[i] = f2b(b[i]);
    else             oc[i] = f2b(c[i]);
}

// ---------------------------------------------------------------------------
// MFMA LSTM cell v5. gates = bias + A1@W1^T + A2@W2^T [+ s*w0col].
// Tile 32 rows x 32 gate-cols (4 gates x 8 j), BK=128.
// grid dim3(64, 32) = 2048 blocks -> 8 blocks/CU, 32 waves/CU (max).
// Flat-bid%8 groups same-j0 blocks onto one XCD (B-slice L2 residency).
// Waves 2x2, each 16 rows x 16 gate-cols: 4 MFMA per wave per K-chunk.
// LDS rows padded to 136 u16. gbuf[32][36] f32 overlays ldsA (post-barrier).
// ---------------------------------------------------------------------------
__global__ __launch_bounds__(256) void k_lstm_m(
    const u16* __restrict__ A1, int lda1, int nk1, const void* __restrict__ W1, int ldw1, int w1f,
    const void* __restrict__ A2, int a2f, int lda2, int nk2, const void* __restrict__ W2, int ldw2, int w2f,
    const float* __restrict__ w0col, const float* __restrict__ s, const float* __restrict__ bias,
    u16* __restrict__ c, u16* __restrict__ hout)
{
    __shared__ __attribute__((aligned(16))) char smem[17408];
    u16*   ldsA = (u16*)smem;                // [32][136] u16, 8704 B
    u16*   ldsB = (u16*)(smem + 8704);       // [32][136] u16, 8704 B
    float* gbuf = (float*)smem;              // [32][36] f32, 4608 B (post-barrier overlay)

    const int tid = threadIdx.x, wid = tid >> 6, lane = tid & 63;
    const int q = lane >> 4, ln = lane & 15;
    const int wr = wid >> 1, wc = wid & 1;           // wave = 16 rows x 16 gate-cols
    const int j0 = blockIdx.x * 8, row0 = blockIdx.y * 32;

    f32x4 acc = f32x4{0.f, 0.f, 0.f, 0.f};

    const int total = nk1 + nk2;
    for (int it = 0; it < total; ++it) {
        const bool h2 = it >= nk1;
        const void* A = h2 ? A2 : (const void*)A1;
        const void* W = h2 ? W2 : W1;
        const int lda = h2 ? lda2 : lda1, ldw = h2 ? ldw2 : ldw1;
        const int af = h2 ? a2f : 0;
        const int wf = h2 ? w2f : w1f;
        const int k0 = (h2 ? it - nk1 : it) * 128;
        __syncthreads();
#pragma unroll
        for (int g = 0; g < 2; ++g) {      // ldsA: 32 rows x 128 k (512 granules)
            int ch = tid + g * 256, r = ch >> 4, cl = (ch & 15) * 8;
            stage8(ldsA + r * 136 + cl, A, (row0 + r) * lda + k0 + cl, af);
        }
#pragma unroll
        for (int g = 0; g < 2; ++g) {      // ldsB: 32 gate-cols x 128 k (512 granules)
            int ch = tid + g * 256, m = ch >> 4, cl = (ch & 15) * 8;
            int wrow = (m >> 3) * 512 + j0 + (m & 7);    // gate (m>>3), col j (m&7)
            stage8(ldsB + m * 136 + cl, W, wrow * ldw + k0 + cl, wf);
        }
        __syncthreads();
#pragma unroll
        for (int ks = 0; ks < 4; ++ks) {
            const int kk = ks * 32 + q * 8;
            bh8 afr = *(const bh8*)(ldsA + (wr * 16 + ln) * 136 + kk);
            bh8 bfr = *(const bh8*)(ldsB + (wc * 16 + ln) * 136 + kk);
            acc = __builtin_amdgcn_mfma_f32_16x16x32_bf16(afr, bfr, acc, 0, 0, 0);
        }
    }
    __syncthreads();
    // C/D layout (measured m89/m91): col = lane&15, row = (lane>>4)*4 + reg
#pragma unroll
    for (int r = 0; r < 4; ++r) {
        int lrow = wr * 16 + q * 4 + r;
        int lcol = wc * 16 + ln;
        gbuf[lrow * 36 + lcol] = acc[r];
    }
    __syncthreads();
    {
        int bl = tid >> 3, j = tid & 7;          // 256 items: 32 rows x 8 j
        int bg = row0 + bl, jg = j0 + j;
        float gi = gbuf[bl * 36 +  0 + j] + bias[jg];
        float gf = gbuf[bl * 36 +  8 + j] + bias[512 + jg];
        float gg = gbuf[bl * 36 + 16 + j] + bias[1024 + jg];
        float go = gbuf[bl * 36 + 24 + j] + bias[1536 + jg];
        if (w0col) {
            float sv = s[bg];
            gi += sv * w0col[jg];         gf += sv * w0col[512 + jg];
            gg += sv * w0col[1024 + jg];  go += sv * w0col[1536 + jg];
        }
        float cold = b2f(c[bg * 512 + jg]);
        float cn = sigf(gf) * cold + sigf(gi) * tanh_(gg);
        float hn = sigf(go) * tanh_(cn);
        c[bg * 512 + jg] = f2b(cn);
        hout[bg * 512 + jg] = f2b(hn);
    }
}

// ---------------------------------------------------------------------------
// Fused f-net (proven R8/R9): pred/gen/bp + f1(MFMA) + f2(MFMA) + f3 + update.
// 16 rows/WG, 64 WGs, 256 threads. f1buf padded to 264.
// ---------------------------------------------------------------------------
__global__ __launch_bounds__(256) void k_fnet(
    int t,
    const u16* __restrict__ h1n, const u16* __restrict__ fW1t, const float* __restrict__ fw1r0,
    const float* __restrict__ fb1, const u16* __restrict__ fW2t, const float* __restrict__ fb2,
    const float* __restrict__ fW3, const float* __restrict__ fb3,
    const float* __restrict__ cW1, const float* __restrict__ cb1,
    const float* __restrict__ cW2, const float* __restrict__ cb2,
    const float* __restrict__ Ee, const float* __restrict__ ratep,
    float* __restrict__ sp, float* __restrict__ out)
{
    __shared__ __attribute__((aligned(16))) u16 ldsA[16 * 64];     // 2KB
    __shared__ __attribute__((aligned(16))) u16 ldsB[256 * 64];    // 32KB
    __shared__ __attribute__((aligned(16))) u16 f1buf[16 * 264];   // 8.25KB (padded)
    __shared__ __attribute__((aligned(16))) float f2buf[16 * 256]; // 16KB
    __shared__ float predb[16];

    const int tid = threadIdx.x, wid = tid >> 6, lane = tid & 63;
    const int q = lane >> 4, ln = lane & 15;
    const int row0 = blockIdx.x * 16;

    // phase 0: pred/gen/bp
#pragma unroll
    for (int pass = 0; pass < 2; ++pass) {
        int rl = wid * 4 + pass * 2 + (lane >> 5);
        int l = lane & 31;
        int bg = row0 + rl;
        float sv = sp[bg], Ev = Ee[bg];
        float z = sv * cW1[l] + Ev * cW1[32 + l] + cb1[l];
        float tv = tanh_(z) * cW2[l];
        tv += __shfl_xor(tv, 1); tv += __shfl_xor(tv, 2); tv += __shfl_xor(tv, 4);
        tv += __shfl_xor(tv, 8); tv += __shfl_xor(tv, 16);
        float gen = ratep[bg] * (1.f - sv);
        float pred = sv + gen + tv + cb2[0];
        if (l == 0) {
            predb[rl] = pred;
            out[OFF_GENS + bg * 32 + t] = gen;
            out[OFF_BPS + bg * 32 + t] = sigf(10.f * (pred - 0.5f));
        }
    }

    // phase 1: f1 = gelu(pred*fw1r0 + h1@fW1t^T + fb1), K=512
    f32x4 acc1[4];
#pragma unroll
    for (int b = 0; b < 4; b++) acc1[b] = f32x4{0.f, 0.f, 0.f, 0.f};
    for (int kc = 0; kc < 8; ++kc) {
        const int k0 = kc * 64;
        __syncthreads();
        if (tid < 128) {
            int r = tid >> 3, cl = (tid & 7) * 8;
            *(float4*)(ldsA + r * 64 + cl) = *(const float4*)(h1n + (row0 + r) * 512 + k0 + cl);
        }
#pragma unroll
        for (int it = 0; it < 8; ++it) {
            int chn = tid + it * 256, m = chn >> 3, cl = (chn & 7) * 8;
            *(float4*)(ldsB + m * 64 + cl) = *(const float4*)(fW1t + m * 512 + k0 + cl);
        }
        __syncthreads();
#pragma unroll
        for (int ks = 0; ks < 2; ++ks) {
            const int kk = ks * 32 + q * 8;
            bh8 a = *(const bh8*)(ldsA + ln * 64 + kk);
#pragma unroll
            for (int nt = 0; nt < 4; ++nt) {
                bh8 b = *(const bh8*)(ldsB + (wid * 64 + nt * 16 + ln) * 64 + kk);
                acc1[nt] = __builtin_amdgcn_mfma_f32_16x16x32_bf16(a, b, acc1[nt], 0, 0, 0);
            }
        }
    }
    __syncthreads();
#pragma unroll
    for (int nt = 0; nt < 4; ++nt)
#pragma unroll
        for (int r = 0; r < 4; ++r) {
            int row = q * 4 + r;
            int col = wid * 64 + nt * 16 + ln;
            float x = acc1[nt][r] + fb1[col] + predb[row] * fw1r0[col];
            f1buf[row * 264 + col] = f2b(gelu_(x));
        }

    // phase 2: f2 = gelu(f1@fW2t^T + fb2), K=256
    f32x4 acc2[4];
#pragma unroll
    for (int b = 0; b < 4; b++) acc2[b] = f32x4{0.f, 0.f, 0.f, 0.f};
    for (int kc = 0; kc < 4; ++kc) {
        const int k0 = kc * 64;
        __syncthreads();
#pragma unroll
        for (int it = 0; it < 8; ++it) {
            int chn = tid + it * 256, m = chn >> 3, cl = (chn & 7) * 8;
            *(float4*)(ldsB + m * 64 + cl) = *(const float4*)(fW2t + m * 256 + k0 + cl);
        }
        __syncthreads();
#pragma unroll
        for (int ks = 0; ks < 2; ++ks) {
            const int kk = ks * 32 + q * 8;
            bh8 a = *(const bh8*)(f1buf + ln * 264 + k0 + kk);
#pragma unroll
            for (int nt = 0; nt < 4; ++nt) {
                bh8 b = *(const bh8*)(ldsB + (wid * 64 + nt * 16 + ln) * 64 + kk);
                acc2[nt] = __builtin_amdgcn_mfma_f32_16x16x32_bf16(a, b, acc2[nt], 0, 0, 0);
            }
        }
    }
#pragma unroll
    for (int nt = 0; nt < 4; ++nt)
#pragma unroll
        for (int r = 0; r < 4; ++r) {
            int row = q * 4 + r;
            int col = wid * 64 + nt * 16 + ln;
            f2buf[row * 256 + col] = gelu_(acc2[nt][r] + fb2[col]);
        }
    __syncthreads();

    // phase 3: nxt = clip(max(s, f2@fW3 + fb3), 0, 1)
#pragma unroll
    for (int rr = 0; rr < 4; ++rr) {
        int row = wid * 4 + rr;
        f32x4 v = *(const f32x4*)(f2buf + row * 256 + lane * 4);
        float p = v[0] * fW3[lane * 4 + 0] + v[1] * fW3[lane * 4 + 1]
                + v[2] * fW3[lane * 4 + 2] + v[3] * fW3[lane * 4 + 3];
        p += __shfl_xor(p, 1); p += __shfl_xor(p, 2); p += __shfl_xor(p, 4);
        p += __shfl_xor(p, 8); p += __shfl_xor(p, 16); p += __shfl_xor(p, 32);
        if (lane == 0) {
            int bg = row0 + row;
            float nxt = p + fb3[0];
            float sv = sp[bg];
            nxt = fminf(fmaxf(fmaxf(sv, nxt), 0.f), 1.f);
            sp[bg] = nxt;
            out[bg * 32 + t] = nxt;
        }
    }
}

// ---------------------------------------------------------------------------
extern "C" void kernel_launch(void* const* d_in, const int* in_sizes, int n_in,
                              void* d_out, int out_size, void* d_ws, size_t ws_size,
                              hipStream_t stream) {
    const float* ist   = (const float*)d_in[0];
    const float* lat   = (const float*)d_in[1];
    const float* vol   = (const float*)d_in[2];
    const float* thick = (const float*)d_in[3];
    const float* trap  = (const float*)d_in[4];
    const float* W_ih0 = (const float*)d_in[5];
    const float* W_hh0 = (const float*)d_in[6];
    const float* b0_   = (const float*)d_in[7];
    const float* W_ih1 = (const float*)d_in[8];
    const float* W_hh1 = (const float*)d_in[9];
    const float* b1_   = (const float*)d_in[10];
    const float* fW1   = (const float*)d_in[11];
    const float* fb1   = (const float*)d_in[12];
    const float* fW2   = (const float*)d_in[13];
    const float* fb2   = (const float*)d_in[14];
    const float* fW3   = (const float*)d_in[15];
    const float* fb3   = (const float*)d_in[16];
    const float* cW1   = (const float*)d_in[17];
    const float* cb1   = (const float*)d_in[18];
    const float* cW2   = (const float*)d_in[19];
    const float* cb2   = (const float*)d_in[20];

    char* ws = (char*)d_ws;
    u16*   Wp    = (u16*)(ws + WS_WP);
    u16*   fW1t  = (u16*)(ws + WS_FW1T);
    u16*   fW2t  = (u16*)(ws + WS_FW2T);
    float* fw1r0 = (float*)(ws + WS_FW1R0);
    float* w0col = (float*)(ws + WS_W0COL);
    float* Ee    = (float*)(ws + WS_EE);
    float* ratep = (float*)(ws + WS_RATE);
    float* sp    = (float*)(ws + WS_SP);
    u16*   h0    = (u16*)(ws + WS_H0);
    u16*   h1    = (u16*)(ws + WS_H1);
    u16*   c0    = (u16*)(ws + WS_C0);
    u16*   c1    = (u16*)(ws + WS_C1);
    float* out   = (float*)d_out;

    const bool t1 = ws_size >= (size_t)WS_T1_END;   // bf16 W_ih1 + W_hh1
    const bool t2 = ws_size >= (size_t)WS_T2_END;   // + bf16 W_hh0
    u16* wih1b = (u16*)(ws + WS_WIH1B);
    u16* whh1b = (u16*)(ws + WS_WHH1B);
    u16* whh0b = (u16*)(ws + WS_WHH0B);

    k_setup<<<2048, 256, 0, stream>>>(ist, vol, thick, trap, W_ih0, fW1, fW2,
        h0, h1, c0, c1, Wp, w0col, fW1t, fW2t, fw1r0, Ee, ratep, sp, out + OFF_E);
    if (t2) {
        k_conv3w<<<12288, 256, 0, stream>>>(W_ih1, W_hh1, W_hh0, wih1b, whh1b, whh0b);
    } else if (t1) {
        k_conv3w<<<12288, 256, 0, stream>>>(W_ih1, W_hh1, W_hh1, wih1b, whh1b, whh1b);
    }

    const void* pWhh0 = t2 ? (const void*)whh0b : (const void*)W_hh0;
    const void* pWih1 = t1 ? (const void*)wih1b : (const void*)W_ih1;
    const void* pWhh1 = t1 ? (const void*)whh1b : (const void*)W_hh1;
    const int wf0 = t2 ? 0 : 1;
    const int wf1 = t1 ? 0 : 1;

    for (int t = 0; t < 32; ++t) {
        int cur = t & 1, nx = cur ^ 1;
        // lstm0: h0@W_hh0^T (K=512: nk=4) + lat@Wp^T (K=256: nk=2) + s*w0col + b0
        k_lstm_m<<<dim3(64, 32), 256, 0, stream>>>(
            h0 + cur * HS, 512, 4, pWhh0, 512, wf0,
            lat, 1, 256, 2, Wp, 256, 0,
            w0col, sp, b0_, c0, h0 + nx * HS);
        // lstm1: h0n@W_ih1^T (nk=4) + h1@W_hh1^T (nk=4) + b1
        k_lstm_m<<<dim3(64, 32), 256, 0, stream>>>(
            h0 + nx * HS, 512, 4, pWih1, 512, wf1,
            h1 + cur * HS, 0, 512, 4, pWhh1, 512, wf1,
            (const float*)nullptr, (const float*)nullptr, b1_, c1, h1 + nx * HS);
        // fused pred + f-net + state update
        k_fnet<<<64, 256, 0, stream>>>(t, h1 + nx * HS, fW1t, fw1r0, fb1, fW2t, fb2,
            fW3, fb3, cW1, cb1, cW2, cb2, Ee, ratep, sp, out);
    }
}

// Round 14
// 1803.248 us; speedup vs baseline: 4.5856x; 1.0613x over previous
//
#include <hip/hip_runtime.h>
#include <hip/hip_bf16.h>

typedef unsigned short u16;
typedef unsigned int u32;
typedef __attribute__((ext_vector_type(8))) short bh8;     // 8 x bf16 MFMA A/B frag
typedef __attribute__((ext_vector_type(4))) float f32x4;   // MFMA C/D frag

#define KB_T 0.025851f
#define HS (1024 * 512)

// d_out (fp32): preds.T [1024][32] | E [1024] | gens.T [1024][32] | bps.T [1024][32]
#define OFF_E    32768
#define OFF_GENS 33792
#define OFF_BPS  66560

// ---- workspace layout (byte offsets)
#define WS_WP     0u         // [2048][256] bf16  (W_ih0[:,1:])
#define WS_FW1T   1048576u   // [256][512] bf16   (fW1[1:] ^T)
#define WS_FW2T   1310720u   // [256][256] bf16   (fW2 ^T)
#define WS_FW1R0  1441792u   // [256] f32         (fW1 row 0)
#define WS_W0COL  1442816u   // [2048] f32        (W_ih0[:,0])
#define WS_EE     1451008u   // [1024] f32
#define WS_RATE   1455104u   // [1024] f32
#define WS_SP     1459200u   // [1024] f32
#define WS_H0     1463296u   // 2x[1024][512] bf16 ping-pong
#define WS_H1     3560448u   // 2x[1024][512] bf16
#define WS_C0     5657600u   // [1024][512] bf16
#define WS_C1     6706176u   // [1024][512] bf16
#define WS_BASE_END 7754752u
// tier1 (ws >= 11949056): bf16 W_ih1 + W_hh1. tier2 (ws >= 14046208): + W_hh0
#define WS_WIH1B  7754752u
#define WS_WHH1B  9851904u
#define WS_T1_END 11949056u
#define WS_WHH0B  11949056u
#define WS_T2_END 14046208u

__device__ __forceinline__ float b2f(u16 u) { u32 x = ((u32)u) << 16; float f; __builtin_memcpy(&f, &x, 4); return f; }
__device__ __forceinline__ u16 f2b(float f) { __hip_bfloat16 h = __float2bfloat16(f); u16 u; __builtin_memcpy(&u, &h, 2); return u; }
__device__ __forceinline__ float sigf(float x) { return 1.f / (1.f + __expf(-x)); }
__device__ __forceinline__ float tanh_(float x) { return 1.f - 2.f / (__expf(2.f * x) + 1.f); }
__device__ __forceinline__ float gelu_(float x) { return 0.5f * x * (1.f + tanh_(0.7978845608f * (x + 0.044715f * x * x * x))); }

// stage 8 contiguous elements into LDS as bf16; src bf16 (16B copy) or fp32 (32B + cvt)
__device__ __forceinline__ void stage8(u16* dst, const void* src, int ofs, int srcf32) {
    if (srcf32) {
        const float* s = (const float*)src + ofs;
        float4 a = *(const float4*)s;
        float4 b = *(const float4*)(s + 4);
        u16 t[8] = {f2b(a.x), f2b(a.y), f2b(a.z), f2b(a.w),
                    f2b(b.x), f2b(b.y), f2b(b.z), f2b(b.w)};
        *(float4*)dst = *(const float4*)t;
    } else {
        *(float4*)dst = *(const float4*)((const u16*)src + ofs);
    }
}

// ---------------------------------------------------------------------------
// setup (proven): zero states; repack W_ih0 -> Wp+w0col; fW1 -> fW1t+fw1r0;
// fW2 -> fW2t; E/rate/s0. grid 2048 x 256.
// ---------------------------------------------------------------------------
__global__ __launch_bounds__(256) void k_setup(
    const float* __restrict__ ist, const float* __restrict__ vol, const float* __restrict__ thick,
    const float* __restrict__ trap, const float* __restrict__ W_ih0,
    const float* __restrict__ fW1, const float* __restrict__ fW2,
    u16* __restrict__ h0, u16* __restrict__ h1, u16* __restrict__ c0, u16* __restrict__ c1,
    u16* __restrict__ Wp, float* __restrict__ w0col,
    u16* __restrict__ fW1t, u16* __restrict__ fW2t, float* __restrict__ fw1r0,
    float* __restrict__ Ee, float* __restrict__ ratep, float* __restrict__ sp,
    float* __restrict__ outE)
{
    const int idx = blockIdx.x * 256 + threadIdx.x;
    h0[idx] = 0; h1[idx] = 0; c0[idx] = 0; c1[idx] = 0;
    Wp[idx] = f2b(W_ih0[(idx >> 8) * 257 + 1 + (idx & 255)]);
    if (idx < 131072) { int n = idx >> 9, k = idx & 511; fW1t[n * 512 + k] = f2b(fW1[(1 + k) * 256 + n]); }
    if (idx < 65536)  { int n = idx >> 8, k = idx & 255; fW2t[n * 256 + k] = f2b(fW2[k * 256 + n]); }
    if (idx < 2048)   w0col[idx] = W_ih0[idx * 257];
    if (idx < 256)    fw1r0[idx] = fW1[idx];
    if (idx < 1024) {
        float E = vol[idx] / thick[idx];
        float Ea = trap[idx * 8], ga = trap[idx * 8 + 1];
        ratep[idx] = __expf(-fmaxf(Ea - ga * E, 0.f) / KB_T);
        Ee[idx] = E;
        sp[idx] = ist[idx * 10 + 9];
        outE[idx] = E;
    }
}

// fp32 -> bf16 convert of three [2048][512] weights in one launch. grid 12288 x 256.
__global__ __launch_bounds__(256) void k_conv3w(
    const float* __restrict__ a, const float* __restrict__ b, const float* __restrict__ c,
    u16* __restrict__ oa, u16* __restrict__ ob, u16* __restrict__ oc)
{
    const int idx = blockIdx.x * 256 + threadIdx.x;   // [0, 3145728)
    const int w = idx >> 20, i = idx & 1048575;
    if (w == 0)      oa[i] = f2b(a[i]);
    else if (w == 1) ob[i] = f2b(b[i]);
    else             oc[i] = f2b(c[i]);
}

// ---------------------------------------------------------------------------
// MFMA LSTM cell v6. gates = bias + A1@W1^T + A2@W2^T [+ s*w0col].
// Tile 32 rows x 64 gate-cols (4 gates x 16 j), BK=128, 512 threads (8 waves,
// 2x4 of 16x16). grid dim3(32, 32) = 1024 blocks -> 4 blocks/CU, 32 waves/CU
// (max occupancy) at 25% less staging traffic than the 32x32 tile.
// LDS rows padded to 136 u16. gbuf[32][68] f32 overlays ldsA (post-barrier).
// ---------------------------------------------------------------------------
__global__ __launch_bounds__(512) void k_lstm_m(
    const u16* __restrict__ A1, int lda1, int nk1, const void* __restrict__ W1, int ldw1, int w1f,
    const void* __restrict__ A2, int a2f, int lda2, int nk2, const void* __restrict__ W2, int ldw2, int w2f,
    const float* __restrict__ w0col, const float* __restrict__ s, const float* __restrict__ bias,
    u16* __restrict__ c, u16* __restrict__ hout)
{
    __shared__ __attribute__((aligned(16))) char smem[26112];
    u16*   ldsA = (u16*)smem;                // [32][136] u16, 8704 B
    u16*   ldsB = (u16*)(smem + 8704);       // [64][136] u16, 17408 B
    float* gbuf = (float*)smem;              // [32][68] f32, 8704 B (post-barrier overlay)

    const int tid = threadIdx.x, wid = tid >> 6, lane = tid & 63;
    const int q = lane >> 4, ln = lane & 15;
    const int wr = wid >> 2, wc = wid & 3;           // wave = 16 rows x 16 gate-cols
    const int j0 = blockIdx.x * 16, row0 = blockIdx.y * 32;

    f32x4 acc = f32x4{0.f, 0.f, 0.f, 0.f};

    const int total = nk1 + nk2;
    for (int it = 0; it < total; ++it) {
        const bool h2 = it >= nk1;
        const void* A = h2 ? A2 : (const void*)A1;
        const void* W = h2 ? W2 : W1;
        const int lda = h2 ? lda2 : lda1, ldw = h2 ? ldw2 : ldw1;
        const int af = h2 ? a2f : 0;
        const int wf = h2 ? w2f : w1f;
        const int k0 = (h2 ? it - nk1 : it) * 128;
        __syncthreads();
        {   // ldsA: 32 rows x 128 k (512 granules, 1/thread)
            int r = tid >> 4, cl = (tid & 15) * 8;
            stage8(ldsA + r * 136 + cl, A, (row0 + r) * lda + k0 + cl, af);
        }
#pragma unroll
        for (int g = 0; g < 2; ++g) {      // ldsB: 64 gate-cols x 128 k (1024 granules)
            int ch = tid + g * 512, m = ch >> 4, cl = (ch & 15) * 8;
            int wrow = (m >> 4) * 512 + j0 + (m & 15);   // gate (m>>4), col j (m&15)
            stage8(ldsB + m * 136 + cl, W, wrow * ldw + k0 + cl, wf);
        }
        __syncthreads();
#pragma unroll
        for (int ks = 0; ks < 4; ++ks) {
            const int kk = ks * 32 + q * 8;
            bh8 afr = *(const bh8*)(ldsA + (wr * 16 + ln) * 136 + kk);
            bh8 bfr = *(const bh8*)(ldsB + (wc * 16 + ln) * 136 + kk);
            acc = __builtin_amdgcn_mfma_f32_16x16x32_bf16(afr, bfr, acc, 0, 0, 0);
        }
    }
    __syncthreads();
    // C/D layout (measured m89/m91): col = lane&15, row = (lane>>4)*4 + reg
#pragma unroll
    for (int r = 0; r < 4; ++r) {
        int lrow = wr * 16 + q * 4 + r;
        int lcol = wc * 16 + ln;
        gbuf[lrow * 68 + lcol] = acc[r];
    }
    __syncthreads();
    {
        int bl = tid >> 4, j = tid & 15;         // 512 items: 32 rows x 16 j
        int bg = row0 + bl, jg = j0 + j;
        float gi = gbuf[bl * 68 +  0 + j] + bias[jg];
        float gf = gbuf[bl * 68 + 16 + j] + bias[512 + jg];
        float gg = gbuf[bl * 68 + 32 + j] + bias[1024 + jg];
        float go = gbuf[bl * 68 + 48 + j] + bias[1536 + jg];
        if (w0col) {
            float sv = s[bg];
            gi += sv * w0col[jg];         gf += sv * w0col[512 + jg];
            gg += sv * w0col[1024 + jg];  go += sv * w0col[1536 + jg];
        }
        float cold = b2f(c[bg * 512 + jg]);
        float cn = sigf(gf) * cold + sigf(gi) * tanh_(gg);
        float hn = sigf(go) * tanh_(cn);
        c[bg * 512 + jg] = f2b(cn);
        hout[bg * 512 + jg] = f2b(hn);
    }
}

// ---------------------------------------------------------------------------
// Fused f-net (proven R8/R9): pred/gen/bp + f1(MFMA) + f2(MFMA) + f3 + update.
// 16 rows/WG, 64 WGs, 256 threads. f1buf padded to 264.
// ---------------------------------------------------------------------------
__global__ __launch_bounds__(256) void k_fnet(
    int t,
    const u16* __restrict__ h1n, const u16* __restrict__ fW1t, const float* __restrict__ fw1r0,
    const float* __restrict__ fb1, const u16* __restrict__ fW2t, const float* __restrict__ fb2,
    const float* __restrict__ fW3, const float* __restrict__ fb3,
    const float* __restrict__ cW1, const float* __restrict__ cb1,
    const float* __restrict__ cW2, const float* __restrict__ cb2,
    const float* __restrict__ Ee, const float* __restrict__ ratep,
    float* __restrict__ sp, float* __restrict__ out)
{
    __shared__ __attribute__((aligned(16))) u16 ldsA[16 * 64];     // 2KB
    __shared__ __attribute__((aligned(16))) u16 ldsB[256 * 64];    // 32KB
    __shared__ __attribute__((aligned(16))) u16 f1buf[16 * 264];   // 8.25KB (padded)
    __shared__ __attribute__((aligned(16))) float f2buf[16 * 256]; // 16KB
    __shared__ float predb[16];

    const int tid = threadIdx.x, wid = tid >> 6, lane = tid & 63;
    const int q = lane >> 4, ln = lane & 15;
    const int row0 = blockIdx.x * 16;

    // phase 0: pred/gen/bp
#pragma unroll
    for (int pass = 0; pass < 2; ++pass) {
        int rl = wid * 4 + pass * 2 + (lane >> 5);
        int l = lane & 31;
        int bg = row0 + rl;
        float sv = sp[bg], Ev = Ee[bg];
        float z = sv * cW1[l] + Ev * cW1[32 + l] + cb1[l];
        float tv = tanh_(z) * cW2[l];
        tv += __shfl_xor(tv, 1); tv += __shfl_xor(tv, 2); tv += __shfl_xor(tv, 4);
        tv += __shfl_xor(tv, 8); tv += __shfl_xor(tv, 16);
        float gen = ratep[bg] * (1.f - sv);
        float pred = sv + gen + tv + cb2[0];
        if (l == 0) {
            predb[rl] = pred;
            out[OFF_GENS + bg * 32 + t] = gen;
            out[OFF_BPS + bg * 32 + t] = sigf(10.f * (pred - 0.5f));
        }
    }

    // phase 1: f1 = gelu(pred*fw1r0 + h1@fW1t^T + fb1), K=512
    f32x4 acc1[4];
#pragma unroll
    for (int b = 0; b < 4; b++) acc1[b] = f32x4{0.f, 0.f, 0.f, 0.f};
    for (int kc = 0; kc < 8; ++kc) {
        const int k0 = kc * 64;
        __syncthreads();
        if (tid < 128) {
            int r = tid >> 3, cl = (tid & 7) * 8;
            *(float4*)(ldsA + r * 64 + cl) = *(const float4*)(h1n + (row0 + r) * 512 + k0 + cl);
        }
#pragma unroll
        for (int it = 0; it < 8; ++it) {
            int chn = tid + it * 256, m = chn >> 3, cl = (chn & 7) * 8;
            *(float4*)(ldsB + m * 64 + cl) = *(const float4*)(fW1t + m * 512 + k0 + cl);
        }
        __syncthreads();
#pragma unroll
        for (int ks = 0; ks < 2; ++ks) {
            const int kk = ks * 32 + q * 8;
            bh8 a = *(const bh8*)(ldsA + ln * 64 + kk);
#pragma unroll
            for (int nt = 0; nt < 4; ++nt) {
                bh8 b = *(const bh8*)(ldsB + (wid * 64 + nt * 16 + ln) * 64 + kk);
                acc1[nt] = __builtin_amdgcn_mfma_f32_16x16x32_bf16(a, b, acc1[nt], 0, 0, 0);
            }
        }
    }
    __syncthreads();
#pragma unroll
    for (int nt = 0; nt < 4; ++nt)
#pragma unroll
        for (int r = 0; r < 4; ++r) {
            int row = q * 4 + r;
            int col = wid * 64 + nt * 16 + ln;
            float x = acc1[nt][r] + fb1[col] + predb[row] * fw1r0[col];
            f1buf[row * 264 + col] = f2b(gelu_(x));
        }

    // phase 2: f2 = gelu(f1@fW2t^T + fb2), K=256
    f32x4 acc2[4];
#pragma unroll
    for (int b = 0; b < 4; b++) acc2[b] = f32x4{0.f, 0.f, 0.f, 0.f};
    for (int kc = 0; kc < 4; ++kc) {
        const int k0 = kc * 64;
        __syncthreads();
#pragma unroll
        for (int it = 0; it < 8; ++it) {
            int chn = tid + it * 256, m = chn >> 3, cl = (chn & 7) * 8;
            *(float4*)(ldsB + m * 64 + cl) = *(const float4*)(fW2t + m * 256 + k0 + cl);
        }
        __syncthreads();
#pragma unroll
        for (int ks = 0; ks < 2; ++ks) {
            const int kk = ks * 32 + q * 8;
            bh8 a = *(const bh8*)(f1buf + ln * 264 + k0 + kk);
#pragma unroll
            for (int nt = 0; nt < 4; ++nt) {
                bh8 b = *(const bh8*)(ldsB + (wid * 64 + nt * 16 + ln) * 64 + kk);
                acc2[nt] = __builtin_amdgcn_mfma_f32_16x16x32_bf16(a, b, acc2[nt], 0, 0, 0);
            }
        }
    }
#pragma unroll
    for (int nt = 0; nt < 4; ++nt)
#pragma unroll
        for (int r = 0; r < 4; ++r) {
            int row = q * 4 + r;
            int col = wid * 64 + nt * 16 + ln;
            f2buf[row * 256 + col] = gelu_(acc2[nt][r] + fb2[col]);
        }
    __syncthreads();

    // phase 3: nxt = clip(max(s, f2@fW3 + fb3), 0, 1)
#pragma unroll
    for (int rr = 0; rr < 4; ++rr) {
        int row = wid * 4 + rr;
        f32x4 v = *(const f32x4*)(f2buf + row * 256 + lane * 4);
        float p = v[0] * fW3[lane * 4 + 0] + v[1] * fW3[lane * 4 + 1]
                + v[2] * fW3[lane * 4 + 2] + v[3] * fW3[lane * 4 + 3];
        p += __shfl_xor(p, 1); p += __shfl_xor(p, 2); p += __shfl_xor(p, 4);
        p += __shfl_xor(p, 8); p += __shfl_xor(p, 16); p += __shfl_xor(p, 32);
        if (lane == 0) {
            int bg = row0 + row;
            float nxt = p + fb3[0];
            float sv = sp[bg];
            nxt = fminf(fmaxf(fmaxf(sv, nxt), 0.f), 1.f);
            sp[bg] = nxt;
            out[bg * 32 + t] = nxt;
        }
    }
}

// ---------------------------------------------------------------------------
extern "C" void kernel_launch(void* const* d_in, const int* in_sizes, int n_in,
                              void* d_out, int out_size, void* d_ws, size_t ws_size,
                              hipStream_t stream) {
    const float* ist   = (const float*)d_in[0];
    const float* lat   = (const float*)d_in[1];
    const float* vol   = (const float*)d_in[2];
    const float* thick = (const float*)d_in[3];
    const float* trap  = (const float*)d_in[4];
    const float* W_ih0 = (const float*)d_in[5];
    const float* W_hh0 = (const float*)d_in[6];
    const float* b0_   = (const float*)d_in[7];
    const float* W_ih1 = (const float*)d_in[8];
    const float* W_hh1 = (const float*)d_in[9];
    const float* b1_   = (const float*)d_in[10];
    const float* fW1   = (const float*)d_in[11];
    const float* fb1   = (const float*)d_in[12];
    const float* fW2   = (const float*)d_in[13];
    const float* fb2   = (const float*)d_in[14];
    const float* fW3   = (const float*)d_in[15];
    const float* fb3   = (const float*)d_in[16];
    const float* cW1   = (const float*)d_in[17];
    const float* cb1   = (const float*)d_in[18];
    const float* cW2   = (const float*)d_in[19];
    const float* cb2   = (const float*)d_in[20];

    char* ws = (char*)d_ws;
    u16*   Wp    = (u16*)(ws + WS_WP);
    u16*   fW1t  = (u16*)(ws + WS_FW1T);
    u16*   fW2t  = (u16*)(ws + WS_FW2T);
    float* fw1r0 = (float*)(ws + WS_FW1R0);
    float* w0col = (float*)(ws + WS_W0COL);
    float* Ee    = (float*)(ws + WS_EE);
    float* ratep = (float*)(ws + WS_RATE);
    float* sp    = (float*)(ws + WS_SP);
    u16*   h0    = (u16*)(ws + WS_H0);
    u16*   h1    = (u16*)(ws + WS_H1);
    u16*   c0    = (u16*)(ws + WS_C0);
    u16*   c1    = (u16*)(ws + WS_C1);
    float* out   = (float*)d_out;

    const bool t1 = ws_size >= (size_t)WS_T1_END;   // bf16 W_ih1 + W_hh1
    const bool t2 = ws_size >= (size_t)WS_T2_END;   // + bf16 W_hh0
    u16* wih1b = (u16*)(ws + WS_WIH1B);
    u16* whh1b = (u16*)(ws + WS_WHH1B);
    u16* whh0b = (u16*)(ws + WS_WHH0B);

    k_setup<<<2048, 256, 0, stream>>>(ist, vol, thick, trap, W_ih0, fW1, fW2,
        h0, h1, c0, c1, Wp, w0col, fW1t, fW2t, fw1r0, Ee, ratep, sp, out + OFF_E);
    if (t2) {
        k_conv3w<<<12288, 256, 0, stream>>>(W_ih1, W_hh1, W_hh0, wih1b, whh1b, whh0b);
    } else if (t1) {
        k_conv3w<<<12288, 256, 0, stream>>>(W_ih1, W_hh1, W_hh1, wih1b, whh1b, whh1b);
    }

    const void* pWhh0 = t2 ? (const void*)whh0b : (const void*)W_hh0;
    const void* pWih1 = t1 ? (const void*)wih1b : (const void*)W_ih1;
    const void* pWhh1 = t1 ? (const void*)whh1b : (const void*)W_hh1;
    const int wf0 = t2 ? 0 : 1;
    const int wf1 = t1 ? 0 : 1;

    for (int t = 0; t < 32; ++t) {
        int cur = t & 1, nx = cur ^ 1;
        // lstm0: h0@W_hh0^T (K=512: nk=4) + lat@Wp^T (K=256: nk=2) + s*w0col + b0
        k_lstm_m<<<dim3(32, 32), 512, 0, stream>>>(
            h0 + cur * HS, 512, 4, pWhh0, 512, wf0,
            lat, 1, 256, 2, Wp, 256, 0,
            w0col, sp, b0_, c0, h0 + nx * HS);
        // lstm1: h0n@W_ih1^T (nk=4) + h1@W_hh1^T (nk=4) + b1
        k_lstm_m<<<dim3(32, 32), 512, 0, stream>>>(
            h0 + nx * HS, 512, 4, pWih1, 512, wf1,
            h1 + cur * HS, 0, 512, 4, pWhh1, 512, wf1,
            (const float*)nullptr, (const float*)nullptr, b1_, c1, h1 + nx * HS);
        // fused pred + f-net + state update
        k_fnet<<<64, 256, 0, stream>>>(t, h1 + nx * HS, fW1t, fw1r0, fb1, fW2t, fb2,
            fW3, fb3, cW1, cb1, cW2, cb2, Ee, ratep, sp, out);
    }
}

// Round 15
// 1726.218 us; speedup vs baseline: 4.7902x; 1.0446x over previous
//
#include <hip/hip_runtime.h>
#include <hip/hip_bf16.h>

typedef unsigned short u16;
typedef unsigned int u32;
typedef __attribute__((ext_vector_type(8))) short bh8;     // 8 x bf16 MFMA A/B frag
typedef __attribute__((ext_vector_type(4))) float f32x4;   // MFMA C/D frag

#define KB_T 0.025851f
#define HS (1024 * 512)

// d_out (fp32): preds.T [1024][32] | E [1024] | gens.T [1024][32] | bps.T [1024][32]
#define OFF_E    32768
#define OFF_GENS 33792
#define OFF_BPS  66560

// ---- workspace layout (byte offsets)
#define WS_WP     0u         // [2048][256] bf16  (W_ih0[:,1:])
#define WS_FW1T   1048576u   // [256][512] bf16   (fW1[1:] ^T)
#define WS_FW2T   1310720u   // [256][256] bf16   (fW2 ^T)
#define WS_FW1R0  1441792u   // [256] f32         (fW1 row 0)
#define WS_W0COL  1442816u   // [2048] f32        (W_ih0[:,0])
#define WS_EE     1451008u   // [1024] f32
#define WS_RATE   1455104u   // [1024] f32
#define WS_SP     1459200u   // [1024] f32
#define WS_H0     1463296u   // 2x[1024][512] bf16 ping-pong
#define WS_H1     3560448u   // 2x[1024][512] bf16
#define WS_C0     5657600u   // [1024][512] bf16
#define WS_C1     6706176u   // [1024][512] bf16
#define WS_BASE_END 7754752u
// tier1 (ws >= 11949056): bf16 W_ih1 + W_hh1. tier2 (ws >= 14046208): + W_hh0
#define WS_WIH1B  7754752u
#define WS_WHH1B  9851904u
#define WS_T1_END 11949056u
#define WS_WHH0B  11949056u
#define WS_T2_END 14046208u
// tier3 (ws >= 22434816): lp = b0 + lat@Wp^T, fp32 [1024][2048]
#define WS_LP     14046208u
#define WS_T3_END 22434816u

__device__ __forceinline__ float b2f(u16 u) { u32 x = ((u32)u) << 16; float f; __builtin_memcpy(&f, &x, 4); return f; }
__device__ __forceinline__ u16 f2b(float f) { __hip_bfloat16 h = __float2bfloat16(f); u16 u; __builtin_memcpy(&u, &h, 2); return u; }
__device__ __forceinline__ float sigf(float x) { return 1.f / (1.f + __expf(-x)); }
__device__ __forceinline__ float tanh_(float x) { return 1.f - 2.f / (__expf(2.f * x) + 1.f); }
__device__ __forceinline__ float gelu_(float x) { return 0.5f * x * (1.f + tanh_(0.7978845608f * (x + 0.044715f * x * x * x))); }

// stage 8 contiguous elements into LDS as bf16; src bf16 (16B copy) or fp32 (32B + cvt)
__device__ __forceinline__ void stage8(u16* dst, const void* src, int ofs, int srcf32) {
    if (srcf32) {
        const float* s = (const float*)src + ofs;
        float4 a = *(const float4*)s;
        float4 b = *(const float4*)(s + 4);
        u16 t[8] = {f2b(a.x), f2b(a.y), f2b(a.z), f2b(a.w),
                    f2b(b.x), f2b(b.y), f2b(b.z), f2b(b.w)};
        *(float4*)dst = *(const float4*)t;
    } else {
        *(float4*)dst = *(const float4*)((const u16*)src + ofs);
    }
}

// ---------------------------------------------------------------------------
// setup (proven): zero states; repack W_ih0 -> Wp+w0col; fW1 -> fW1t+fw1r0;
// fW2 -> fW2t; E/rate/s0. grid 2048 x 256.
// ---------------------------------------------------------------------------
__global__ __launch_bounds__(256) void k_setup(
    const float* __restrict__ ist, const float* __restrict__ vol, const float* __restrict__ thick,
    const float* __restrict__ trap, const float* __restrict__ W_ih0,
    const float* __restrict__ fW1, const float* __restrict__ fW2,
    u16* __restrict__ h0, u16* __restrict__ h1, u16* __restrict__ c0, u16* __restrict__ c1,
    u16* __restrict__ Wp, float* __restrict__ w0col,
    u16* __restrict__ fW1t, u16* __restrict__ fW2t, float* __restrict__ fw1r0,
    float* __restrict__ Ee, float* __restrict__ ratep, float* __restrict__ sp,
    float* __restrict__ outE)
{
    const int idx = blockIdx.x * 256 + threadIdx.x;
    h0[idx] = 0; h1[idx] = 0; c0[idx] = 0; c1[idx] = 0;
    Wp[idx] = f2b(W_ih0[(idx >> 8) * 257 + 1 + (idx & 255)]);
    if (idx < 131072) { int n = idx >> 9, k = idx & 511; fW1t[n * 512 + k] = f2b(fW1[(1 + k) * 256 + n]); }
    if (idx < 65536)  { int n = idx >> 8, k = idx & 255; fW2t[n * 256 + k] = f2b(fW2[k * 256 + n]); }
    if (idx < 2048)   w0col[idx] = W_ih0[idx * 257];
    if (idx < 256)    fw1r0[idx] = fW1[idx];
    if (idx < 1024) {
        float E = vol[idx] / thick[idx];
        float Ea = trap[idx * 8], ga = trap[idx * 8 + 1];
        ratep[idx] = __expf(-fmaxf(Ea - ga * E, 0.f) / KB_T);
        Ee[idx] = E;
        sp[idx] = ist[idx * 10 + 9];
        outE[idx] = E;
    }
}

// fp32 -> bf16 convert of three [2048][512] weights in one launch. grid 12288 x 256.
__global__ __launch_bounds__(256) void k_conv3w(
    const float* __restrict__ a, const float* __restrict__ b, const float* __restrict__ c,
    u16* __restrict__ oa, u16* __restrict__ ob, u16* __restrict__ oc)
{
    const int idx = blockIdx.x * 256 + threadIdx.x;   // [0, 3145728)
    const int w = idx >> 20, i = idx & 1048575;
    if (w == 0)      oa[i] = f2b(a[i]);
    else if (w == 1) ob[i] = f2b(b[i]);
    else             oc[i] = f2b(c[i]);
}

// ---------------------------------------------------------------------------
// One-time latent projection: lp[b][n] = b0[n] + sum_k lat[b][k]*Wp[n][k]
// (M=1024, N=2048, K=256). v6 tile geometry: 32 rows x 64 n, BK=128,
// 512 threads (8 waves of 16x16). grid dim3(32, 32).
// ---------------------------------------------------------------------------
__global__ __launch_bounds__(512) void k_latent(
    const float* __restrict__ lat, const u16* __restrict__ Wp,
    const float* __restrict__ b0, float* __restrict__ lp)
{
    __shared__ __attribute__((aligned(16))) char smem[26112];
    u16* ldsA = (u16*)smem;                // [32][136] u16
    u16* ldsB = (u16*)(smem + 8704);       // [64][136] u16

    const int tid = threadIdx.x, wid = tid >> 6, lane = tid & 63;
    const int q = lane >> 4, ln = lane & 15;
    const int wr = wid >> 2, wc = wid & 3;           // wave = 16 rows x 16 n
    const int n0 = blockIdx.x * 64, row0 = blockIdx.y * 32;

    f32x4 acc = f32x4{0.f, 0.f, 0.f, 0.f};
    for (int it = 0; it < 2; ++it) {
        const int k0 = it * 128;
        __syncthreads();
        {   // ldsA: 32 rows x 128 k from fp32 lat
            int r = tid >> 4, cl = (tid & 15) * 8;
            stage8(ldsA + r * 136 + cl, lat, (row0 + r) * 256 + k0 + cl, 1);
        }
#pragma unroll
        for (int g = 0; g < 2; ++g) {      // ldsB: 64 n x 128 k from bf16 Wp
            int ch = tid + g * 512, m = ch >> 4, cl = (ch & 15) * 8;
            stage8(ldsB + m * 136 + cl, Wp, (n0 + m) * 256 + k0 + cl, 0);
        }
        __syncthreads();
#pragma unroll
        for (int ks = 0; ks < 4; ++ks) {
            const int kk = ks * 32 + q * 8;
            bh8 afr = *(const bh8*)(ldsA + (wr * 16 + ln) * 136 + kk);
            bh8 bfr = *(const bh8*)(ldsB + (wc * 16 + ln) * 136 + kk);
            acc = __builtin_amdgcn_mfma_f32_16x16x32_bf16(afr, bfr, acc, 0, 0, 0);
        }
    }
    // C/D layout (measured m89/m91): col = lane&15, row = (lane>>4)*4 + reg
#pragma unroll
    for (int r = 0; r < 4; ++r) {
        int row = row0 + wr * 16 + q * 4 + r;
        int col = n0 + wc * 16 + ln;
        lp[row * 2048 + col] = acc[r] + b0[col];
    }
}

// ---------------------------------------------------------------------------
// MFMA LSTM cell v6+lp. gates = A1@W1^T [+ A2@W2^T] + (lp-row | bias) [+ s*w0col].
// Tile 32 rows x 64 gate-cols (4 gates x 16 j), BK=128, 512 threads (8 waves).
// grid dim3(32, 32) = 1024 blocks -> 4 blocks/CU, 32 waves/CU (max occupancy).
// LDS rows padded to 136 u16. gbuf[32][68] f32 overlays ldsA (post-barrier).
// ---------------------------------------------------------------------------
__global__ __launch_bounds__(512) void k_lstm_m(
    const u16* __restrict__ A1, int lda1, int nk1, const void* __restrict__ W1, int ldw1, int w1f,
    const void* __restrict__ A2, int a2f, int lda2, int nk2, const void* __restrict__ W2, int ldw2, int w2f,
    const float* __restrict__ w0col, const float* __restrict__ s, const float* __restrict__ bias,
    const float* __restrict__ lp,
    u16* __restrict__ c, u16* __restrict__ hout)
{
    __shared__ __attribute__((aligned(16))) char smem[26112];
    u16*   ldsA = (u16*)smem;                // [32][136] u16, 8704 B
    u16*   ldsB = (u16*)(smem + 8704);       // [64][136] u16, 17408 B
    float* gbuf = (float*)smem;              // [32][68] f32, 8704 B (post-barrier overlay)

    const int tid = threadIdx.x, wid = tid >> 6, lane = tid & 63;
    const int q = lane >> 4, ln = lane & 15;
    const int wr = wid >> 2, wc = wid & 3;           // wave = 16 rows x 16 gate-cols
    const int j0 = blockIdx.x * 16, row0 = blockIdx.y * 32;

    f32x4 acc = f32x4{0.f, 0.f, 0.f, 0.f};

    const int total = nk1 + nk2;
    for (int it = 0; it < total; ++it) {
        const bool h2 = it >= nk1;
        const void* A = h2 ? A2 : (const void*)A1;
        const void* W = h2 ? W2 : W1;
        const int lda = h2 ? lda2 : lda1, ldw = h2 ? ldw2 : ldw1;
        const int af = h2 ? a2f : 0;
        const int wf = h2 ? w2f : w1f;
        const int k0 = (h2 ? it - nk1 : it) * 128;
        __syncthreads();
        {   // ldsA: 32 rows x 128 k (512 granules, 1/thread)
            int r = tid >> 4, cl = (tid & 15) * 8;
            stage8(ldsA + r * 136 + cl, A, (row0 + r) * lda + k0 + cl, af);
        }
#pragma unroll
        for (int g = 0; g < 2; ++g) {      // ldsB: 64 gate-cols x 128 k (1024 granules)
            int ch = tid + g * 512, m = ch >> 4, cl = (ch & 15) * 8;
            int wrow = (m >> 4) * 512 + j0 + (m & 15);   // gate (m>>4), col j (m&15)
            stage8(ldsB + m * 136 + cl, W, wrow * ldw + k0 + cl, wf);
        }
        __syncthreads();
#pragma unroll
        for (int ks = 0; ks < 4; ++ks) {
            const int kk = ks * 32 + q * 8;
            bh8 afr = *(const bh8*)(ldsA + (wr * 16 + ln) * 136 + kk);
            bh8 bfr = *(const bh8*)(ldsB + (wc * 16 + ln) * 136 + kk);
            acc = __builtin_amdgcn_mfma_f32_16x16x32_bf16(afr, bfr, acc, 0, 0, 0);
        }
    }
    __syncthreads();
    // C/D layout (measured m89/m91): col = lane&15, row = (lane>>4)*4 + reg
#pragma unroll
    for (int r = 0; r < 4; ++r) {
        int lrow = wr * 16 + q * 4 + r;
        int lcol = wc * 16 + ln;
        gbuf[lrow * 68 + lcol] = acc[r];
    }
    __syncthreads();
    {
        int bl = tid >> 4, j = tid & 15;         // 512 items: 32 rows x 16 j
        int bg = row0 + bl, jg = j0 + j;
        float gi = gbuf[bl * 68 +  0 + j];
        float gf = gbuf[bl * 68 + 16 + j];
        float gg = gbuf[bl * 68 + 32 + j];
        float go = gbuf[bl * 68 + 48 + j];
        if (lp) {
            gi += lp[bg * 2048 + jg];          gf += lp[bg * 2048 + 512 + jg];
            gg += lp[bg * 2048 + 1024 + jg];   go += lp[bg * 2048 + 1536 + jg];
        } else if (bias) {
            gi += bias[jg];        gf += bias[512 + jg];
            gg += bias[1024 + jg]; go += bias[1536 + jg];
        }
        if (w0col) {
            float sv = s[bg];
            gi += sv * w0col[jg];         gf += sv * w0col[512 + jg];
            gg += sv * w0col[1024 + jg];  go += sv * w0col[1536 + jg];
        }
        float cold = b2f(c[bg * 512 + jg]);
        float cn = sigf(gf) * cold + sigf(gi) * tanh_(gg);
        float hn = sigf(go) * tanh_(cn);
        c[bg * 512 + jg] = f2b(cn);
        hout[bg * 512 + jg] = f2b(hn);
    }
}

// ---------------------------------------------------------------------------
// Fused f-net (proven R8/R9): pred/gen/bp + f1(MFMA) + f2(MFMA) + f3 + update.
// 16 rows/WG, 64 WGs, 256 threads. f1buf padded to 264.
// ---------------------------------------------------------------------------
__global__ __launch_bounds__(256) void k_fnet(
    int t,
    const u16* __restrict__ h1n, const u16* __restrict__ fW1t, const float* __restrict__ fw1r0,
    const float* __restrict__ fb1, const u16* __restrict__ fW2t, const float* __restrict__ fb2,
    const float* __restrict__ fW3, const float* __restrict__ fb3,
    const float* __restrict__ cW1, const float* __restrict__ cb1,
    const float* __restrict__ cW2, const float* __restrict__ cb2,
    const float* __restrict__ Ee, const float* __restrict__ ratep,
    float* __restrict__ sp, float* __restrict__ out)
{
    __shared__ __attribute__((aligned(16))) u16 ldsA[16 * 64];     // 2KB
    __shared__ __attribute__((aligned(16))) u16 ldsB[256 * 64];    // 32KB
    __shared__ __attribute__((aligned(16))) u16 f1buf[16 * 264];   // 8.25KB (padded)
    __shared__ __attribute__((aligned(16))) float f2buf[16 * 256]; // 16KB
    __shared__ float predb[16];

    const int tid = threadIdx.x, wid = tid >> 6, lane = tid & 63;
    const int q = lane >> 4, ln = lane & 15;
    const int row0 = blockIdx.x * 16;

    // phase 0: pred/gen/bp
#pragma unroll
    for (int pass = 0; pass < 2; ++pass) {
        int rl = wid * 4 + pass * 2 + (lane >> 5);
        int l = lane & 31;
        int bg = row0 + rl;
        float sv = sp[bg], Ev = Ee[bg];
        float z = sv * cW1[l] + Ev * cW1[32 + l] + cb1[l];
        float tv = tanh_(z) * cW2[l];
        tv += __shfl_xor(tv, 1); tv += __shfl_xor(tv, 2); tv += __shfl_xor(tv, 4);
        tv += __shfl_xor(tv, 8); tv += __shfl_xor(tv, 16);
        float gen = ratep[bg] * (1.f - sv);
        float pred = sv + gen + tv + cb2[0];
        if (l == 0) {
            predb[rl] = pred;
            out[OFF_GENS + bg * 32 + t] = gen;
            out[OFF_BPS + bg * 32 + t] = sigf(10.f * (pred - 0.5f));
        }
    }

    // phase 1: f1 = gelu(pred*fw1r0 + h1@fW1t^T + fb1), K=512
    f32x4 acc1[4];
#pragma unroll
    for (int b = 0; b < 4; b++) acc1[b] = f32x4{0.f, 0.f, 0.f, 0.f};
    for (int kc = 0; kc < 8; ++kc) {
        const int k0 = kc * 64;
        __syncthreads();
        if (tid < 128) {
            int r = tid >> 3, cl = (tid & 7) * 8;
            *(float4*)(ldsA + r * 64 + cl) = *(const float4*)(h1n + (row0 + r) * 512 + k0 + cl);
        }
#pragma unroll
        for (int it = 0; it < 8; ++it) {
            int chn = tid + it * 256, m = chn >> 3, cl = (chn & 7) * 8;
            *(float4*)(ldsB + m * 64 + cl) = *(const float4*)(fW1t + m * 512 + k0 + cl);
        }
        __syncthreads();
#pragma unroll
        for (int ks = 0; ks < 2; ++ks) {
            const int kk = ks * 32 + q * 8;
            bh8 a = *(const bh8*)(ldsA + ln * 64 + kk);
#pragma unroll
            for (int nt = 0; nt < 4; ++nt) {
                bh8 b = *(const bh8*)(ldsB + (wid * 64 + nt * 16 + ln) * 64 + kk);
                acc1[nt] = __builtin_amdgcn_mfma_f32_16x16x32_bf16(a, b, acc1[nt], 0, 0, 0);
            }
        }
    }
    __syncthreads();
#pragma unroll
    for (int nt = 0; nt < 4; ++nt)
#pragma unroll
        for (int r = 0; r < 4; ++r) {
            int row = q * 4 + r;
            int col = wid * 64 + nt * 16 + ln;
            float x = acc1[nt][r] + fb1[col] + predb[row] * fw1r0[col];
            f1buf[row * 264 + col] = f2b(gelu_(x));
        }

    // phase 2: f2 = gelu(f1@fW2t^T + fb2), K=256
    f32x4 acc2[4];
#pragma unroll
    for (int b = 0; b < 4; b++) acc2[b] = f32x4{0.f, 0.f, 0.f, 0.f};
    for (int kc = 0; kc < 4; ++kc) {
        const int k0 = kc * 64;
        __syncthreads();
#pragma unroll
        for (int it = 0; it < 8; ++it) {
            int chn = tid + it * 256, m = chn >> 3, cl = (chn & 7) * 8;
            *(float4*)(ldsB + m * 64 + cl) = *(const float4*)(fW2t + m * 256 + k0 + cl);
        }
        __syncthreads();
#pragma unroll
        for (int ks = 0; ks < 2; ++ks) {
            const int kk = ks * 32 + q * 8;
            bh8 a = *(const bh8*)(f1buf + ln * 264 + k0 + kk);
#pragma unroll
            for (int nt = 0; nt < 4; ++nt) {
                bh8 b = *(const bh8*)(ldsB + (wid * 64 + nt * 16 + ln) * 64 + kk);
                acc2[nt] = __builtin_amdgcn_mfma_f32_16x16x32_bf16(a, b, acc2[nt], 0, 0, 0);
            }
        }
    }
#pragma unroll
    for (int nt = 0; nt < 4; ++nt)
#pragma unroll
        for (int r = 0; r < 4; ++r) {
            int row = q * 4 + r;
            int col = wid * 64 + nt * 16 + ln;
            f2buf[row * 256 + col] = gelu_(acc2[nt][r] + fb2[col]);
        }
    __syncthreads();

    // phase 3: nxt = clip(max(s, f2@fW3 + fb3), 0, 1)
#pragma unroll
    for (int rr = 0; rr < 4; ++rr) {
        int row = wid * 4 + rr;
        f32x4 v = *(const f32x4*)(f2buf + row * 256 + lane * 4);
        float p = v[0] * fW3[lane * 4 + 0] + v[1] * fW3[lane * 4 + 1]
                + v[2] * fW3[lane * 4 + 2] + v[3] * fW3[lane * 4 + 3];
        p += __shfl_xor(p, 1); p += __shfl_xor(p, 2); p += __shfl_xor(p, 4);
        p += __shfl_xor(p, 8); p += __shfl_xor(p, 16); p += __shfl_xor(p, 32);
        if (lane == 0) {
            int bg = row0 + row;
            float nxt = p + fb3[0];
            float sv = sp[bg];
            nxt = fminf(fmaxf(fmaxf(sv, nxt), 0.f), 1.f);
            sp[bg] = nxt;
            out[bg * 32 + t] = nxt;
        }
    }
}

// ---------------------------------------------------------------------------
extern "C" void kernel_launch(void* const* d_in, const int* in_sizes, int n_in,
                              void* d_out, int out_size, void* d_ws, size_t ws_size,
                              hipStream_t stream) {
    const float* ist   = (const float*)d_in[0];
    const float* lat   = (const float*)d_in[1];
    const float* vol   = (const float*)d_in[2];
    const float* thick = (const float*)d_in[3];
    const float* trap  = (const float*)d_in[4];
    const float* W_ih0 = (const float*)d_in[5];
    const float* W_hh0 = (const float*)d_in[6];
    const float* b0_   = (const float*)d_in[7];
    const float* W_ih1 = (const float*)d_in[8];
    const float* W_hh1 = (const float*)d_in[9];
    const float* b1_   = (const float*)d_in[10];
    const float* fW1   = (const float*)d_in[11];
    const float* fb1   = (const float*)d_in[12];
    const float* fW2   = (const float*)d_in[13];
    const float* fb2   = (const float*)d_in[14];
    const float* fW3   = (const float*)d_in[15];
    const float* fb3   = (const float*)d_in[16];
    const float* cW1   = (const float*)d_in[17];
    const float* cb1   = (const float*)d_in[18];
    const float* cW2   = (const float*)d_in[19];
    const float* cb2   = (const float*)d_in[20];

    char* ws = (char*)d_ws;
    u16*   Wp    = (u16*)(ws + WS_WP);
    u16*   fW1t  = (u16*)(ws + WS_FW1T);
    u16*   fW2t  = (u16*)(ws + WS_FW2T);
    float* fw1r0 = (float*)(ws + WS_FW1R0);
    float* w0col = (float*)(ws + WS_W0COL);
    float* Ee    = (float*)(ws + WS_EE);
    float* ratep = (float*)(ws + WS_RATE);
    float* sp    = (float*)(ws + WS_SP);
    u16*   h0    = (u16*)(ws + WS_H0);
    u16*   h1    = (u16*)(ws + WS_H1);
    u16*   c0    = (u16*)(ws + WS_C0);
    u16*   c1    = (u16*)(ws + WS_C1);
    float* lp    = (float*)(ws + WS_LP);
    float* out   = (float*)d_out;

    const bool t1 = ws_size >= (size_t)WS_T1_END;   // bf16 W_ih1 + W_hh1
    const bool t2 = ws_size >= (size_t)WS_T2_END;   // + bf16 W_hh0
    const bool t3 = ws_size >= (size_t)WS_T3_END;   // + precomputed lp
    u16* wih1b = (u16*)(ws + WS_WIH1B);
    u16* whh1b = (u16*)(ws + WS_WHH1B);
    u16* whh0b = (u16*)(ws + WS_WHH0B);

    k_setup<<<2048, 256, 0, stream>>>(ist, vol, thick, trap, W_ih0, fW1, fW2,
        h0, h1, c0, c1, Wp, w0col, fW1t, fW2t, fw1r0, Ee, ratep, sp, out + OFF_E);
    if (t2) {
        k_conv3w<<<12288, 256, 0, stream>>>(W_ih1, W_hh1, W_hh0, wih1b, whh1b, whh0b);
    } else if (t1) {
        k_conv3w<<<12288, 256, 0, stream>>>(W_ih1, W_hh1, W_hh1, wih1b, whh1b, whh1b);
    }
    if (t3)
        k_latent<<<dim3(32, 32), 512, 0, stream>>>(lat, Wp, b0_, lp);

    const void* pWhh0 = t2 ? (const void*)whh0b : (const void*)W_hh0;
    const void* pWih1 = t1 ? (const void*)wih1b : (const void*)W_ih1;
    const void* pWhh1 = t1 ? (const void*)whh1b : (const void*)W_hh1;
    const int wf0 = t2 ? 0 : 1;
    const int wf1 = t1 ? 0 : 1;

    for (int t = 0; t < 32; ++t) {
        int cur = t & 1, nx = cur ^ 1;
        if (t3) {
            // lstm0: h0@W_hh0^T (K=512: nk=4) + lp (incl. b0 + lat proj) + s*w0col
            k_lstm_m<<<dim3(32, 32), 512, 0, stream>>>(
                h0 + cur * HS, 512, 4, pWhh0, 512, wf0,
                (const void*)nullptr, 0, 0, 0, (const void*)nullptr, 0, 0,
                w0col, sp, (const float*)nullptr, lp, c0, h0 + nx * HS);
        } else {
            // fallback: two-half lstm0
            k_lstm_m<<<dim3(32, 32), 512, 0, stream>>>(
                h0 + cur * HS, 512, 4, pWhh0, 512, wf0,
                lat, 1, 256, 2, Wp, 256, 0,
                w0col, sp, b0_, (const float*)nullptr, c0, h0 + nx * HS);
        }
        // lstm1: h0n@W_ih1^T (nk=4) + h1@W_hh1^T (nk=4) + b1
        k_lstm_m<<<dim3(32, 32), 512, 0, stream>>>(
            h0 + nx * HS, 512, 4, pWih1, 512, wf1,
            h1 + cur * HS, 0, 512, 4, pWhh1, 512, wf1,
            (const float*)nullptr, (const float*)nullptr, b1_, (const float*)nullptr,
            c1, h1 + nx * HS);
        // fused pred + f-net + state update
        k_fnet<<<64, 256, 0, stream>>>(t, h1 + nx * HS, fW1t, fw1r0, fb1, fW2t, fb2,
            fW3, fb3, cW1, cb1, cW2, cb2, Ee, ratep, sp, out);
    }
}

// Round 16
// 1654.736 us; speedup vs baseline: 4.9972x; 1.0432x over previous
//
#include <hip/hip_runtime.h>
#include <hip/hip_bf16.h>

typedef unsigned short u16;
typedef unsigned int u32;
typedef __attribute__((ext_vector_type(8))) short bh8;     // 8 x bf16 MFMA A/B frag
typedef __attribute__((ext_vector_type(4))) float f32x4;   // MFMA C/D frag

#define KB_T 0.025851f
#define HS (1024 * 512)

// d_out (fp32): preds.T [1024][32] | E [1024] | gens.T [1024][32] | bps.T [1024][32]
#define OFF_E    32768
#define OFF_GENS 33792
#define OFF_BPS  66560

// ---- workspace layout (byte offsets)
#define WS_WP     0u         // [2048][256] bf16  (W_ih0[:,1:])
#define WS_FW1T   1048576u   // [256][512] bf16   (fW1[1:] ^T)
#define WS_FW2T   1310720u   // [256][256] bf16   (fW2 ^T)
#define WS_FW1R0  1441792u   // [256] f32         (fW1 row 0)
#define WS_W0COL  1442816u   // [2048] f32        (W_ih0[:,0])
#define WS_EE     1451008u   // [1024] f32
#define WS_RATE   1455104u   // [1024] f32
#define WS_SP     1459200u   // [1024] f32
#define WS_H0     1463296u   // 2x[1024][512] bf16 ping-pong
#define WS_H1     3560448u   // 2x[1024][512] bf16
#define WS_C0     5657600u   // [1024][512] bf16
#define WS_C1     6706176u   // [1024][512] bf16
#define WS_BASE_END 7754752u
// tier1 (ws >= 11949056): bf16 W_ih1 + W_hh1. tier2 (ws >= 14046208): + W_hh0
#define WS_WIH1B  7754752u
#define WS_WHH1B  9851904u
#define WS_T1_END 11949056u
#define WS_WHH0B  11949056u
#define WS_T2_END 14046208u
// tier3 (ws >= 22434816): lp = b0 + lat@Wp^T, fp32 [1024][2048]
#define WS_LP     14046208u
#define WS_T3_END 22434816u

__device__ __forceinline__ float b2f(u16 u) { u32 x = ((u32)u) << 16; float f; __builtin_memcpy(&f, &x, 4); return f; }
__device__ __forceinline__ u16 f2b(float f) { __hip_bfloat16 h = __float2bfloat16(f); u16 u; __builtin_memcpy(&u, &h, 2); return u; }
__device__ __forceinline__ float sigf(float x) { return 1.f / (1.f + __expf(-x)); }
__device__ __forceinline__ float tanh_(float x) { return 1.f - 2.f / (__expf(2.f * x) + 1.f); }
__device__ __forceinline__ float gelu_(float x) { return 0.5f * x * (1.f + tanh_(0.7978845608f * (x + 0.044715f * x * x * x))); }

// stage 8 contiguous elements into LDS as bf16; src bf16 (16B copy) or fp32 (32B + cvt)
__device__ __forceinline__ void stage8(u16* dst, const void* src, int ofs, int srcf32) {
    if (srcf32) {
        const float* s = (const float*)src + ofs;
        float4 a = *(const float4*)s;
        float4 b = *(const float4*)(s + 4);
        u16 t[8] = {f2b(a.x), f2b(a.y), f2b(a.z), f2b(a.w),
                    f2b(b.x), f2b(b.y), f2b(b.z), f2b(b.w)};
        *(float4*)dst = *(const float4*)t;
    } else {
        *(float4*)dst = *(const float4*)((const u16*)src + ofs);
    }
}

// ---------------------------------------------------------------------------
// setup (proven): zero states; repack W_ih0 -> Wp+w0col; fW1 -> fW1t+fw1r0;
// fW2 -> fW2t; E/rate/s0. grid 2048 x 256.
// ---------------------------------------------------------------------------
__global__ __launch_bounds__(256) void k_setup(
    const float* __restrict__ ist, const float* __restrict__ vol, const float* __restrict__ thick,
    const float* __restrict__ trap, const float* __restrict__ W_ih0,
    const float* __restrict__ fW1, const float* __restrict__ fW2,
    u16* __restrict__ h0, u16* __restrict__ h1, u16* __restrict__ c0, u16* __restrict__ c1,
    u16* __restrict__ Wp, float* __restrict__ w0col,
    u16* __restrict__ fW1t, u16* __restrict__ fW2t, float* __restrict__ fw1r0,
    float* __restrict__ Ee, float* __restrict__ ratep, float* __restrict__ sp,
    float* __restrict__ outE)
{
    const int idx = blockIdx.x * 256 + threadIdx.x;
    h0[idx] = 0; h1[idx] = 0; c0[idx] = 0; c1[idx] = 0;
    Wp[idx] = f2b(W_ih0[(idx >> 8) * 257 + 1 + (idx & 255)]);
    if (idx < 131072) { int n = idx >> 9, k = idx & 511; fW1t[n * 512 + k] = f2b(fW1[(1 + k) * 256 + n]); }
    if (idx < 65536)  { int n = idx >> 8, k = idx & 255; fW2t[n * 256 + k] = f2b(fW2[k * 256 + n]); }
    if (idx < 2048)   w0col[idx] = W_ih0[idx * 257];
    if (idx < 256)    fw1r0[idx] = fW1[idx];
    if (idx < 1024) {
        float E = vol[idx] / thick[idx];
        float Ea = trap[idx * 8], ga = trap[idx * 8 + 1];
        ratep[idx] = __expf(-fmaxf(Ea - ga * E, 0.f) / KB_T);
        Ee[idx] = E;
        sp[idx] = ist[idx * 10 + 9];
        outE[idx] = E;
    }
}

// fp32 -> bf16 convert of three [2048][512] weights in one launch. grid 12288 x 256.
__global__ __launch_bounds__(256) void k_conv3w(
    const float* __restrict__ a, const float* __restrict__ b, const float* __restrict__ c,
    u16* __restrict__ oa, u16* __restrict__ ob, u16* __restrict__ oc)
{
    const int idx = blockIdx.x * 256 + threadIdx.x;   // [0, 3145728)
    const int w = idx >> 20, i = idx & 1048575;
    if (w == 0)      oa[i] = f2b(a[i]);
    else if (w == 1) ob[i] = f2b(b[i]);
    else             oc[i] = f2b(c[i]);
}

// ---------------------------------------------------------------------------
// One-time latent projection: lp[b][n] = b0[n] + sum_k lat[b][k]*Wp[n][k]
// (M=1024, N=2048, K=256). v6 tile geometry. grid dim3(32, 32) x 512.
// ---------------------------------------------------------------------------
__global__ __launch_bounds__(512) void k_latent(
    const float* __restrict__ lat, const u16* __restrict__ Wp,
    const float* __restrict__ b0, float* __restrict__ lp)
{
    __shared__ __attribute__((aligned(16))) char smem[26112];
    u16* ldsA = (u16*)smem;                // [32][136] u16
    u16* ldsB = (u16*)(smem + 8704);       // [64][136] u16

    const int tid = threadIdx.x, wid = tid >> 6, lane = tid & 63;
    const int q = lane >> 4, ln = lane & 15;
    const int wr = wid >> 2, wc = wid & 3;           // wave = 16 rows x 16 n
    const int n0 = blockIdx.x * 64, row0 = blockIdx.y * 32;

    f32x4 acc = f32x4{0.f, 0.f, 0.f, 0.f};
    for (int it = 0; it < 2; ++it) {
        const int k0 = it * 128;
        __syncthreads();
        {   // ldsA: 32 rows x 128 k from fp32 lat
            int r = tid >> 4, cl = (tid & 15) * 8;
            stage8(ldsA + r * 136 + cl, lat, (row0 + r) * 256 + k0 + cl, 1);
        }
#pragma unroll
        for (int g = 0; g < 2; ++g) {      // ldsB: 64 n x 128 k from bf16 Wp
            int ch = tid + g * 512, m = ch >> 4, cl = (ch & 15) * 8;
            stage8(ldsB + m * 136 + cl, Wp, (n0 + m) * 256 + k0 + cl, 0);
        }
        __syncthreads();
#pragma unroll
        for (int ks = 0; ks < 4; ++ks) {
            const int kk = ks * 32 + q * 8;
            bh8 afr = *(const bh8*)(ldsA + (wr * 16 + ln) * 136 + kk);
            bh8 bfr = *(const bh8*)(ldsB + (wc * 16 + ln) * 136 + kk);
            acc = __builtin_amdgcn_mfma_f32_16x16x32_bf16(afr, bfr, acc, 0, 0, 0);
        }
    }
    // C/D layout (measured m89/m91): col = lane&15, row = (lane>>4)*4 + reg
#pragma unroll
    for (int r = 0; r < 4; ++r) {
        int row = row0 + wr * 16 + q * 4 + r;
        int col = n0 + wc * 16 + ln;
        lp[row * 2048 + col] = acc[r] + b0[col];
    }
}

// ---------------------------------------------------------------------------
// MFMA LSTM cell v6+lp (proven R15). gates = A1@W1^T [+ A2@W2^T]
// + (lp-row | bias) [+ s*w0col]. Tile 32 rows x 64 gate-cols, BK=128,
// 512 threads. grid dim3(32, 32) -> 4 blocks/CU, 32 waves/CU.
// ---------------------------------------------------------------------------
__global__ __launch_bounds__(512) void k_lstm_m(
    const u16* __restrict__ A1, int lda1, int nk1, const void* __restrict__ W1, int ldw1, int w1f,
    const void* __restrict__ A2, int a2f, int lda2, int nk2, const void* __restrict__ W2, int ldw2, int w2f,
    const float* __restrict__ w0col, const float* __restrict__ s, const float* __restrict__ bias,
    const float* __restrict__ lp,
    u16* __restrict__ c, u16* __restrict__ hout)
{
    __shared__ __attribute__((aligned(16))) char smem[26112];
    u16*   ldsA = (u16*)smem;                // [32][136] u16, 8704 B
    u16*   ldsB = (u16*)(smem + 8704);       // [64][136] u16, 17408 B
    float* gbuf = (float*)smem;              // [32][68] f32, 8704 B (post-barrier overlay)

    const int tid = threadIdx.x, wid = tid >> 6, lane = tid & 63;
    const int q = lane >> 4, ln = lane & 15;
    const int wr = wid >> 2, wc = wid & 3;           // wave = 16 rows x 16 gate-cols
    const int j0 = blockIdx.x * 16, row0 = blockIdx.y * 32;

    f32x4 acc = f32x4{0.f, 0.f, 0.f, 0.f};

    const int total = nk1 + nk2;
    for (int it = 0; it < total; ++it) {
        const bool h2 = it >= nk1;
        const void* A = h2 ? A2 : (const void*)A1;
        const void* W = h2 ? W2 : W1;
        const int lda = h2 ? lda2 : lda1, ldw = h2 ? ldw2 : ldw1;
        const int af = h2 ? a2f : 0;
        const int wf = h2 ? w2f : w1f;
        const int k0 = (h2 ? it - nk1 : it) * 128;
        __syncthreads();
        {   // ldsA: 32 rows x 128 k (512 granules, 1/thread)
            int r = tid >> 4, cl = (tid & 15) * 8;
            stage8(ldsA + r * 136 + cl, A, (row0 + r) * lda + k0 + cl, af);
        }
#pragma unroll
        for (int g = 0; g < 2; ++g) {      // ldsB: 64 gate-cols x 128 k (1024 granules)
            int ch = tid + g * 512, m = ch >> 4, cl = (ch & 15) * 8;
            int wrow = (m >> 4) * 512 + j0 + (m & 15);   // gate (m>>4), col j (m&15)
            stage8(ldsB + m * 136 + cl, W, wrow * ldw + k0 + cl, wf);
        }
        __syncthreads();
#pragma unroll
        for (int ks = 0; ks < 4; ++ks) {
            const int kk = ks * 32 + q * 8;
            bh8 afr = *(const bh8*)(ldsA + (wr * 16 + ln) * 136 + kk);
            bh8 bfr = *(const bh8*)(ldsB + (wc * 16 + ln) * 136 + kk);
            acc = __builtin_amdgcn_mfma_f32_16x16x32_bf16(afr, bfr, acc, 0, 0, 0);
        }
    }
    __syncthreads();
    // C/D layout (measured m89/m91): col = lane&15, row = (lane>>4)*4 + reg
#pragma unroll
    for (int r = 0; r < 4; ++r) {
        int lrow = wr * 16 + q * 4 + r;
        int lcol = wc * 16 + ln;
        gbuf[lrow * 68 + lcol] = acc[r];
    }
    __syncthreads();
    {
        int bl = tid >> 4, j = tid & 15;         // 512 items: 32 rows x 16 j
        int bg = row0 + bl, jg = j0 + j;
        float gi = gbuf[bl * 68 +  0 + j];
        float gf = gbuf[bl * 68 + 16 + j];
        float gg = gbuf[bl * 68 + 32 + j];
        float go = gbuf[bl * 68 + 48 + j];
        if (lp) {
            gi += lp[bg * 2048 + jg];          gf += lp[bg * 2048 + 512 + jg];
            gg += lp[bg * 2048 + 1024 + jg];   go += lp[bg * 2048 + 1536 + jg];
        } else if (bias) {
            gi += bias[jg];        gf += bias[512 + jg];
            gg += bias[1024 + jg]; go += bias[1536 + jg];
        }
        if (w0col) {
            float sv = s[bg];
            gi += sv * w0col[jg];         gf += sv * w0col[512 + jg];
            gg += sv * w0col[1024 + jg];  go += sv * w0col[1536 + jg];
        }
        float cold = b2f(c[bg * 512 + jg]);
        float cn = sigf(gf) * cold + sigf(gi) * tanh_(gg);
        float hn = sigf(go) * tanh_(cn);
        c[bg * 512 + jg] = f2b(cn);
        hout[bg * 512 + jg] = f2b(hn);
    }
}

// ---------------------------------------------------------------------------
// Fused f-net v2: 512 threads (8 waves) — double the resident waves in the
// serial stage->barrier->MFMA chain. 16 rows/WG, 64 WGs. Same LDS/phases as
// the proven 256-thread version; each wave handles 2 n-tiles of 16.
// ---------------------------------------------------------------------------
__global__ __launch_bounds__(512) void k_fnet(
    int t,
    const u16* __restrict__ h1n, const u16* __restrict__ fW1t, const float* __restrict__ fw1r0,
    const float* __restrict__ fb1, const u16* __restrict__ fW2t, const float* __restrict__ fb2,
    const float* __restrict__ fW3, const float* __restrict__ fb3,
    const float* __restrict__ cW1, const float* __restrict__ cb1,
    const float* __restrict__ cW2, const float* __restrict__ cb2,
    const float* __restrict__ Ee, const float* __restrict__ ratep,
    float* __restrict__ sp, float* __restrict__ out)
{
    __shared__ __attribute__((aligned(16))) u16 ldsA[16 * 64];     // 2KB
    __shared__ __attribute__((aligned(16))) u16 ldsB[256 * 64];    // 32KB
    __shared__ __attribute__((aligned(16))) u16 f1buf[16 * 264];   // 8.25KB (padded)
    __shared__ __attribute__((aligned(16))) float f2buf[16 * 256]; // 16KB
    __shared__ float predb[16];

    const int tid = threadIdx.x, wid = tid >> 6, lane = tid & 63;
    const int q = lane >> 4, ln = lane & 15;
    const int row0 = blockIdx.x * 16;

    // phase 0: pred/gen/bp — 16 rows x 32 lanes = 512 threads, one pass
    {
        int rl = wid * 2 + (lane >> 5);
        int l = lane & 31;
        int bg = row0 + rl;
        float sv = sp[bg], Ev = Ee[bg];
        float z = sv * cW1[l] + Ev * cW1[32 + l] + cb1[l];
        float tv = tanh_(z) * cW2[l];
        tv += __shfl_xor(tv, 1); tv += __shfl_xor(tv, 2); tv += __shfl_xor(tv, 4);
        tv += __shfl_xor(tv, 8); tv += __shfl_xor(tv, 16);
        float gen = ratep[bg] * (1.f - sv);
        float pred = sv + gen + tv + cb2[0];
        if (l == 0) {
            predb[rl] = pred;
            out[OFF_GENS + bg * 32 + t] = gen;
            out[OFF_BPS + bg * 32 + t] = sigf(10.f * (pred - 0.5f));
        }
    }

    // phase 1: f1 = gelu(pred*fw1r0 + h1@fW1t^T + fb1), K=512
    f32x4 acc1[2];
    acc1[0] = f32x4{0.f, 0.f, 0.f, 0.f};
    acc1[1] = f32x4{0.f, 0.f, 0.f, 0.f};
    for (int kc = 0; kc < 8; ++kc) {
        const int k0 = kc * 64;
        __syncthreads();
        if (tid < 128) {
            int r = tid >> 3, cl = (tid & 7) * 8;
            *(float4*)(ldsA + r * 64 + cl) = *(const float4*)(h1n + (row0 + r) * 512 + k0 + cl);
        }
#pragma unroll
        for (int it = 0; it < 4; ++it) {
            int chn = tid + it * 512, m = chn >> 3, cl = (chn & 7) * 8;
            *(float4*)(ldsB + m * 64 + cl) = *(const float4*)(fW1t + m * 512 + k0 + cl);
        }
        __syncthreads();
#pragma unroll
        for (int ks = 0; ks < 2; ++ks) {
            const int kk = ks * 32 + q * 8;
            bh8 a = *(const bh8*)(ldsA + ln * 64 + kk);
#pragma unroll
            for (int nt = 0; nt < 2; ++nt) {
                bh8 b = *(const bh8*)(ldsB + (wid * 32 + nt * 16 + ln) * 64 + kk);
                acc1[nt] = __builtin_amdgcn_mfma_f32_16x16x32_bf16(a, b, acc1[nt], 0, 0, 0);
            }
        }
    }
    __syncthreads();
#pragma unroll
    for (int nt = 0; nt < 2; ++nt)
#pragma unroll
        for (int r = 0; r < 4; ++r) {
            int row = q * 4 + r;
            int col = wid * 32 + nt * 16 + ln;
            float x = acc1[nt][r] + fb1[col] + predb[row] * fw1r0[col];
            f1buf[row * 264 + col] = f2b(gelu_(x));
        }

    // phase 2: f2 = gelu(f1@fW2t^T + fb2), K=256
    f32x4 acc2[2];
    acc2[0] = f32x4{0.f, 0.f, 0.f, 0.f};
    acc2[1] = f32x4{0.f, 0.f, 0.f, 0.f};
    for (int kc = 0; kc < 4; ++kc) {
        const int k0 = kc * 64;
        __syncthreads();
#pragma unroll
        for (int it = 0; it < 4; ++it) {
            int chn = tid + it * 512, m = chn >> 3, cl = (chn & 7) * 8;
            *(float4*)(ldsB + m * 64 + cl) = *(const float4*)(fW2t + m * 256 + k0 + cl);
        }
        __syncthreads();
#pragma unroll
        for (int ks = 0; ks < 2; ++ks) {
            const int kk = ks * 32 + q * 8;
            bh8 a = *(const bh8*)(f1buf + ln * 264 + k0 + kk);
#pragma unroll
            for (int nt = 0; nt < 2; ++nt) {
                bh8 b = *(const bh8*)(ldsB + (wid * 32 + nt * 16 + ln) * 64 + kk);
                acc2[nt] = __builtin_amdgcn_mfma_f32_16x16x32_bf16(a, b, acc2[nt], 0, 0, 0);
            }
        }
    }
#pragma unroll
    for (int nt = 0; nt < 2; ++nt)
#pragma unroll
        for (int r = 0; r < 4; ++r) {
            int row = q * 4 + r;
            int col = wid * 32 + nt * 16 + ln;
            f2buf[row * 256 + col] = gelu_(acc2[nt][r] + fb2[col]);
        }
    __syncthreads();

    // phase 3: nxt = clip(max(s, f2@fW3 + fb3), 0, 1) — 2 rows/wave
#pragma unroll
    for (int rr = 0; rr < 2; ++rr) {
        int row = wid * 2 + rr;
        f32x4 v = *(const f32x4*)(f2buf + row * 256 + lane * 4);
        float p = v[0] * fW3[lane * 4 + 0] + v[1] * fW3[lane * 4 + 1]
                + v[2] * fW3[lane * 4 + 2] + v[3] * fW3[lane * 4 + 3];
        p += __shfl_xor(p, 1); p += __shfl_xor(p, 2); p += __shfl_xor(p, 4);
        p += __shfl_xor(p, 8); p += __shfl_xor(p, 16); p += __shfl_xor(p, 32);
        if (lane == 0) {
            int bg = row0 + row;
            float nxt = p + fb3[0];
            float sv = sp[bg];
            nxt = fminf(fmaxf(fmaxf(sv, nxt), 0.f), 1.f);
            sp[bg] = nxt;
            out[bg * 32 + t] = nxt;
        }
    }
}

// ---------------------------------------------------------------------------
extern "C" void kernel_launch(void* const* d_in, const int* in_sizes, int n_in,
                              void* d_out, int out_size, void* d_ws, size_t ws_size,
                              hipStream_t stream) {
    const float* ist   = (const float*)d_in[0];
    const float* lat   = (const float*)d_in[1];
    const float* vol   = (const float*)d_in[2];
    const float* thick = (const float*)d_in[3];
    const float* trap  = (const float*)d_in[4];
    const float* W_ih0 = (const float*)d_in[5];
    const float* W_hh0 = (const float*)d_in[6];
    const float* b0_   = (const float*)d_in[7];
    const float* W_ih1 = (const float*)d_in[8];
    const float* W_hh1 = (const float*)d_in[9];
    const float* b1_   = (const float*)d_in[10];
    const float* fW1   = (const float*)d_in[11];
    const float* fb1   = (const float*)d_in[12];
    const float* fW2   = (const float*)d_in[13];
    const float* fb2   = (const float*)d_in[14];
    const float* fW3   = (const float*)d_in[15];
    const float* fb3   = (const float*)d_in[16];
    const float* cW1   = (const float*)d_in[17];
    const float* cb1   = (const float*)d_in[18];
    const float* cW2   = (const float*)d_in[19];
    const float* cb2   = (const float*)d_in[20];

    char* ws = (char*)d_ws;
    u16*   Wp    = (u16*)(ws + WS_WP);
    u16*   fW1t  = (u16*)(ws + WS_FW1T);
    u16*   fW2t  = (u16*)(ws + WS_FW2T);
    float* fw1r0 = (float*)(ws + WS_FW1R0);
    float* w0col = (float*)(ws + WS_W0COL);
    float* Ee    = (float*)(ws + WS_EE);
    float* ratep = (float*)(ws + WS_RATE);
    float* sp    = (float*)(ws + WS_SP);
    u16*   h0    = (u16*)(ws + WS_H0);
    u16*   h1    = (u16*)(ws + WS_H1);
    u16*   c0    = (u16*)(ws + WS_C0);
    u16*   c1    = (u16*)(ws + WS_C1);
    float* lp    = (float*)(ws + WS_LP);
    float* out   = (float*)d_out;

    const bool t1 = ws_size >= (size_t)WS_T1_END;   // bf16 W_ih1 + W_hh1
    const bool t2 = ws_size >= (size_t)WS_T2_END;   // + bf16 W_hh0
    const bool t3 = ws_size >= (size_t)WS_T3_END;   // + precomputed lp
    u16* wih1b = (u16*)(ws + WS_WIH1B);
    u16* whh1b = (u16*)(ws + WS_WHH1B);
    u16* whh0b = (u16*)(ws + WS_WHH0B);

    k_setup<<<2048, 256, 0, stream>>>(ist, vol, thick, trap, W_ih0, fW1, fW2,
        h0, h1, c0, c1, Wp, w0col, fW1t, fW2t, fw1r0, Ee, ratep, sp, out + OFF_E);
    if (t2) {
        k_conv3w<<<12288, 256, 0, stream>>>(W_ih1, W_hh1, W_hh0, wih1b, whh1b, whh0b);
    } else if (t1) {
        k_conv3w<<<12288, 256, 0, stream>>>(W_ih1, W_hh1, W_hh1, wih1b, whh1b, whh1b);
    }
    if (t3)
        k_latent<<<dim3(32, 32), 512, 0, stream>>>(lat, Wp, b0_, lp);

    const void* pWhh0 = t2 ? (const void*)whh0b : (const void*)W_hh0;
    const void* pWih1 = t1 ? (const void*)wih1b : (const void*)W_ih1;
    const void* pWhh1 = t1 ? (const void*)whh1b : (const void*)W_hh1;
    const int wf0 = t2 ? 0 : 1;
    const int wf1 = t1 ? 0 : 1;

    for (int t = 0; t < 32; ++t) {
        int cur = t & 1, nx = cur ^ 1;
        if (t3) {
            // lstm0: h0@W_hh0^T (K=512: nk=4) + lp (incl. b0 + lat proj) + s*w0col
            k_lstm_m<<<dim3(32, 32), 512, 0, stream>>>(
                h0 + cur * HS, 512, 4, pWhh0, 512, wf0,
                (const void*)nullptr, 0, 0, 0, (const void*)nullptr, 0, 0,
                w0col, sp, (const float*)nullptr, lp, c0, h0 + nx * HS);
        } else {
            // fallback: two-half lstm0
            k_lstm_m<<<dim3(32, 32), 512, 0, stream>>>(
                h0 + cur * HS, 512, 4, pWhh0, 512, wf0,
                lat, 1, 256, 2, Wp, 256, 0,
                w0col, sp, b0_, (const float*)nullptr, c0, h0 + nx * HS);
        }
        // lstm1: h0n@W_ih1^T (nk=4) + h1@W_hh1^T (nk=4) + b1
        k_lstm_m<<<dim3(32, 32), 512, 0, stream>>>(
            h0 + nx * HS, 512, 4, pWih1, 512, wf1,
            h1 + cur * HS, 0, 512, 4, pWhh1, 512, wf1,
            (const float*)nullptr, (const float*)nullptr, b1_, (const float*)nullptr,
            c1, h1 + nx * HS);
        // fused pred + f-net + state update (512 threads, 8 waves)
        k_fnet<<<64, 512, 0, stream>>>(t, h1 + nx * HS, fW1t, fw1r0, fb1, fW2t, fb2,
            fW3, fb3, cW1, cb1, cW2, cb2, Ee, ratep, sp, out);
    }
}